// Round 8
// baseline (521.939 us; speedup 1.0000x reference)
//
#include <hip/hip_runtime.h>
#include <cstdint>

#define NFEAT 4096
#define NHALF 2048
#define DDIM  512
#define QROWS 32768

typedef unsigned short u16;
typedef unsigned char  u8;
typedef unsigned int   u32;
typedef unsigned long long u64;

typedef __bf16 bf16x8_t __attribute__((ext_vector_type(8)));
typedef float  f32x4_t  __attribute__((ext_vector_type(4)));
typedef float  f32x16_t __attribute__((ext_vector_type(16)));
typedef int    i32x4_t  __attribute__((ext_vector_type(4)));
typedef int    i32x8_t  __attribute__((ext_vector_type(8)));
typedef u32    u32x4_t  __attribute__((ext_vector_type(4)));

typedef const __attribute__((address_space(1))) void* gas_ptr;
typedef __attribute__((address_space(3))) void* las_ptr;

__device__ __forceinline__ u16 f2bf(float f) {
  u32 u = __float_as_uint(f);
  u32 r = u + 0x7FFFu + ((u >> 16) & 1u);
  return (u16)(r >> 16);
}

// monotonic unsigned encoding of float (no NaN/Inf expected)
__device__ __forceinline__ u32 fkey(float f) {
  u32 u = __float_as_uint(f);
  return (u & 0x80000000u) ? ~u : (u | 0x80000000u);
}

// ---------------- kernel 1: l2-normalize rows -> bf16 + fp8(e4m3) ----------------
__global__ void k_norm(const float* __restrict__ zi, const float* __restrict__ zj,
                       const float* __restrict__ queue,
                       u16* __restrict__ featb, u16* __restrict__ queueb,
                       u8* __restrict__ feat8, u8* __restrict__ queue8) {
  int gw = (int)((blockIdx.x * blockDim.x + threadIdx.x) >> 6);
  int lane = threadIdx.x & 63;
  const float* src; u16* dst; u8* dst8;
  if (gw < NFEAT) {
    src = (gw < NHALF) ? (zi + (size_t)gw * DDIM) : (zj + (size_t)(gw - NHALF) * DDIM);
    dst = featb + (size_t)gw * DDIM;
    dst8 = feat8 + (size_t)gw * DDIM;
  } else {
    int r = gw - NFEAT;
    src = queue + (size_t)r * DDIM;
    dst = queueb + (size_t)r * DDIM;
    dst8 = queue8 + (size_t)r * DDIM;
  }
  float4 v0 = reinterpret_cast<const float4*>(src)[lane * 2];
  float4 v1 = reinterpret_cast<const float4*>(src)[lane * 2 + 1];
  float ss = v0.x*v0.x + v0.y*v0.y + v0.z*v0.z + v0.w*v0.w
           + v1.x*v1.x + v1.y*v1.y + v1.z*v1.z + v1.w*v1.w;
  #pragma unroll
  for (int off = 32; off >= 1; off >>= 1) ss += __shfl_xor(ss, off);
  float inv = 1.0f / fmaxf(sqrtf(ss), 1e-12f);
  float n0 = v0.x*inv, n1 = v0.y*inv, n2 = v0.z*inv, n3 = v0.w*inv;
  float n4 = v1.x*inv, n5 = v1.y*inv, n6 = v1.z*inv, n7 = v1.w*inv;
  ushort4 o0, o1;
  o0.x = f2bf(n0); o0.y = f2bf(n1); o0.z = f2bf(n2); o0.w = f2bf(n3);
  o1.x = f2bf(n4); o1.y = f2bf(n5); o1.z = f2bf(n6); o1.w = f2bf(n7);
  reinterpret_cast<ushort4*>(dst)[lane * 2]     = o0;
  reinterpret_cast<ushort4*>(dst)[lane * 2 + 1] = o1;
  // fp8 e4m3 pack (v_cvt_pk_fp8_f32: 2 floats -> 2 bytes in low 16 bits)
  u32 p01, p23, p45, p67;
  asm("v_cvt_pk_fp8_f32 %0, %1, %2" : "=v"(p01) : "v"(n0), "v"(n1));
  asm("v_cvt_pk_fp8_f32 %0, %1, %2" : "=v"(p23) : "v"(n2), "v"(n3));
  asm("v_cvt_pk_fp8_f32 %0, %1, %2" : "=v"(p45) : "v"(n4), "v"(n5));
  asm("v_cvt_pk_fp8_f32 %0, %1, %2" : "=v"(p67) : "v"(n6), "v"(n7));
  uint2 w8;
  w8.x = (p01 & 0xFFFFu) | (p23 << 16);
  w8.y = (p45 & 0xFFFFu) | (p67 << 16);
  reinterpret_cast<uint2*>(dst8)[lane] = w8;
}

#define SB0() __builtin_amdgcn_sched_barrier(0)
#define LGKM0_SB() do { asm volatile("s_waitcnt lgkmcnt(0)" ::: "memory"); SB0(); } while (0)
#define LGKM8_SB() do { asm volatile("s_waitcnt lgkmcnt(8)" ::: "memory"); SB0(); } while (0)
#define VMCNT8() asm volatile("s_waitcnt vmcnt(8)" ::: "memory")
#define VMCNT0() asm volatile("s_waitcnt vmcnt(0)" ::: "memory")
#define SBAR() __builtin_amdgcn_s_barrier()
#define RD(dst, base, off) asm volatile("ds_read_b128 %0, %1 offset:" off \
                                        : "=v"(dst) : "v"(base))

// ---------------- kernel 2: fp8 MX GEMM features @ queue^T + fused row-argmax ----
// BM=128, BN=256, BK=64 (fp8 bytes). 512 thr = 8 waves (2M x 4N), wave tile 64x64
// via 32x32x64 f8f6f4 frags (2m x 2n, acc 64 VGPR). LDS/tile = A 8KB + B 16KB;
// dbuf 48 KB -> 2 blocks/CU at launch_bounds(512,4). Scale = 1.0 (E8M0 0x7F).
// LDS swizzle: row r holds its 4 16B-k-slots permuted u = (s + (r>>1)) & 3
// (uniform 8-lane-per-bank-span on ds_read_b128 = minimum 4-way). Staged via
// linear glds dest (lds elem tid*16) + pre-permuted global k-slot.
__global__ __launch_bounds__(512, 4) void k_argmax_gemm8(
    const u8* __restrict__ feat8, const u8* __restrict__ queue8,
    u64* __restrict__ part) {
  __shared__ u8 lds[49152];
  const int tid = threadIdx.x;
  const int w = tid >> 6, lane = tid & 63;
  const int wrm = w >> 2, wcn = w & 3;
  const int l31 = lane & 31, hi = lane >> 5;
  const int bid = (int)blockIdx.x;
  const int wg = (bid & 7) * 512 + (bid >> 3);   // bijective XCD swizzle (4096 = 8x512)
  const int mt = wg & 31, qt = wg >> 5;
  const int brow = mt * 128, bcol = qt * 256;

  // staging: thread covers (row = tid>>2, physical 16B slot tid&3); source slot permuted
  const int srow = tid >> 2;
  const int ss = ((tid & 3) - (srow >> 1)) & 3;
  const u8* pA  = feat8  + (size_t)(brow + srow) * DDIM + ss * 16;
  const u8* pB0 = queue8 + (size_t)(bcol + srow) * DDIM + ss * 16;
  const u8* pB1 = queue8 + (size_t)(bcol + 128 + srow) * DDIM + ss * 16;
  const u32 dA  = (u32)(size_t)(las_ptr)&lds[tid * 16];
  const u32 dB0 = dA + 8192, dB1 = dA + 16384;

  // read-side standing addresses (A: row, B: col); m/n/buf via literal offsets
  const int rA = wrm * 64 + l31;
  const int s0 = hi * 2;
  const u32 aA0 = (u32)(size_t)(las_ptr)&lds[rA * 64 + (((s0    ) + (rA >> 1)) & 3) * 16];
  const u32 aA1 = (u32)(size_t)(las_ptr)&lds[rA * 64 + (((s0 + 1) + (rA >> 1)) & 3) * 16];
  const int cB = wcn * 64 + l31;
  const u32 bB0 = (u32)(size_t)(las_ptr)&lds[8192 + cB * 64 + (((s0    ) + (cB >> 1)) & 3) * 16];
  const u32 bB1 = (u32)(size_t)(las_ptr)&lds[8192 + cB * 64 + (((s0 + 1) + (cB >> 1)) & 3) * 16];

  f32x16_t acc00 = {}, acc01 = {}, acc10 = {}, acc11 = {};

  auto stage = [&](int b, int t) {
    __builtin_amdgcn_global_load_lds((gas_ptr)(pA  + t * 64), (las_ptr)(size_t)(dA  + b * 24576), 16, 0, 0);
    __builtin_amdgcn_global_load_lds((gas_ptr)(pB0 + t * 64), (las_ptr)(size_t)(dB0 + b * 24576), 16, 0, 0);
    __builtin_amdgcn_global_load_lds((gas_ptr)(pB1 + t * 64), (las_ptr)(size_t)(dB1 + b * 24576), 16, 0, 0);
  };

  stage(0, 0);
  VMCNT0();
  SBAR();

  #pragma unroll
  for (int t = 0; t < 8; t++) {
    if (t < 7) stage((t + 1) & 1, t + 1);
    i32x4_t a0l, a0h, a1l, a1h, b0l, b0h, b1l, b1h;
    if ((t & 1) == 0) {
      RD(a0l, aA0, "0");    RD(a0h, aA1, "0");
      RD(a1l, aA0, "2048"); RD(a1h, aA1, "2048");
      RD(b0l, bB0, "0");    RD(b0h, bB1, "0");
      RD(b1l, bB0, "2048"); RD(b1h, bB1, "2048");
    } else {
      RD(a0l, aA0, "24576"); RD(a0h, aA1, "24576");
      RD(a1l, aA0, "26624"); RD(a1h, aA1, "26624");
      RD(b0l, bB0, "24576"); RD(b0h, bB1, "24576");
      RD(b1l, bB0, "26624"); RD(b1h, bB1, "26624");
    }
    LGKM0_SB();
    i32x8_t A0 = __builtin_shufflevector(a0l, a0h, 0, 1, 2, 3, 4, 5, 6, 7);
    i32x8_t A1 = __builtin_shufflevector(a1l, a1h, 0, 1, 2, 3, 4, 5, 6, 7);
    i32x8_t B0 = __builtin_shufflevector(b0l, b0h, 0, 1, 2, 3, 4, 5, 6, 7);
    i32x8_t B1 = __builtin_shufflevector(b1l, b1h, 0, 1, 2, 3, 4, 5, 6, 7);
    __builtin_amdgcn_s_setprio(1);
    acc00 = __builtin_amdgcn_mfma_scale_f32_32x32x64_f8f6f4(A0, B0, acc00, 0, 0, 0, 0x7F7F7F7F, 0, 0x7F7F7F7F);
    acc01 = __builtin_amdgcn_mfma_scale_f32_32x32x64_f8f6f4(A0, B1, acc01, 0, 0, 0, 0x7F7F7F7F, 0, 0x7F7F7F7F);
    acc10 = __builtin_amdgcn_mfma_scale_f32_32x32x64_f8f6f4(A1, B0, acc10, 0, 0, 0, 0x7F7F7F7F, 0, 0x7F7F7F7F);
    acc11 = __builtin_amdgcn_mfma_scale_f32_32x32x64_f8f6f4(A1, B1, acc11, 0, 0, 0, 0x7F7F7F7F, 0, 0x7F7F7F7F);
    __builtin_amdgcn_s_setprio(0);
    if (t < 7) { VMCNT0(); SBAR(); }
  }

  // epilogue: per-row argmax over this block's 256 cols.
  // C/D 32x32 layout: col = lane&31, row = (reg&3) + 8*(reg>>2) + 4*(lane>>5).
  const u32 c0 = (u32)(bcol + wcn * 64 + l31);
  const int rbase = brow + wrm * 64 + 4 * hi;
  const int pslot = (bcol >> 6) + wcn;
  #pragma unroll
  for (int m = 0; m < 2; m++) {
    #pragma unroll
    for (int reg = 0; reg < 16; reg++) {
      float v0 = m == 0 ? acc00[reg] : acc10[reg];
      float v1 = m == 0 ? acc01[reg] : acc11[reg];
      u64 k0 = ((u64)fkey(v0) << 32) | (u64)(0xFFFFFFFFu - c0);
      u64 k1 = ((u64)fkey(v1) << 32) | (u64)(0xFFFFFFFFu - (c0 + 32));
      u64 best = k0 > k1 ? k0 : k1;
      #pragma unroll
      for (int off = 1; off < 32; off <<= 1) {
        u64 o = __shfl_xor(best, off);
        best = best > o ? best : o;
      }
      if (l31 == 0) {
        int row = rbase + m * 32 + (reg & 3) + 8 * (reg >> 2);
        part[(size_t)row * 512 + pslot] = best;
      }
    }
  }
}

// ---------------- kernel 3: reduce argmax partials -> nn_idx ----------------
__global__ void k_argmax_reduce(const u64* __restrict__ part, int* __restrict__ nnidx) {
  int row = (int)((blockIdx.x * blockDim.x + threadIdx.x) >> 6);
  int lane = threadIdx.x & 63;
  const u64* p = part + (size_t)row * 512;
  u64 best = 0;
  #pragma unroll
  for (int i = 0; i < 8; i++) { u64 v = p[lane * 8 + i]; best = best > v ? best : v; }
  #pragma unroll
  for (int off = 1; off < 64; off <<= 1) { u64 o = __shfl_xor(best, off); best = best > o ? best : o; }
  if (lane == 0) nnidx[row] = (int)(0xFFFFFFFFu - (u32)(best & 0xFFFFFFFFu));
}

// ---------------- bf16 pipelined GEMM pieces (k_sim_gemm, unchanged from R7) ----
#define MFMA_Q(MB, NB, AF, BF) do { \
  __builtin_amdgcn_s_setprio(1); \
  _Pragma("unroll") \
  for (int kk_ = 0; kk_ < 2; kk_++) \
    _Pragma("unroll") \
    for (int m_ = 0; m_ < 4; m_++) \
      _Pragma("unroll") \
      for (int n_ = 0; n_ < 2; n_++) \
        acc[MB + m_][NB + n_] = __builtin_amdgcn_mfma_f32_16x16x32_bf16( \
            AF[m_*2+kk_], BF[n_*2+kk_], acc[MB+m_][NB+n_], 0, 0, 0); \
  __builtin_amdgcn_s_setprio(0); } while (0)

#define ISSUE_G1(XA0, XA1, XB0, XB1) do { \
  RD(Bq[0],  XB0, "0");    RD(Bq[1],  XB1, "0");    \
  RD(Bq[2],  XB0, "2048"); RD(Bq[3],  XB1, "2048"); \
  RD(A03[0], XA0, "0");    RD(A03[1], XA1, "0");    \
  RD(A03[2], XA0, "2048"); RD(A03[3], XA1, "2048"); \
  RD(A03[4], XA0, "4096"); RD(A03[5], XA1, "4096"); \
  RD(A03[6], XA0, "6144"); RD(A03[7], XA1, "6144"); } while (0)

#define ISSUE_G2(XA0, XA1, XB0, XB1) do { \
  RD(Bq2[0], XB0, "4096");  RD(Bq2[1], XB1, "4096");  \
  RD(Bq2[2], XB0, "6144");  RD(Bq2[3], XB1, "6144");  \
  RD(A47[0], XA0, "8192");  RD(A47[1], XA1, "8192");  \
  RD(A47[2], XA0, "10240"); RD(A47[3], XA1, "10240"); \
  RD(A47[4], XA0, "12288"); RD(A47[5], XA1, "12288"); \
  RD(A47[6], XA0, "14336"); RD(A47[7], XA1, "14336"); } while (0)

#define GEMM_MAIN_LOOP() do { \
  stTile(0, 0); stTile(1, 1); \
  VMCNT8(); \
  SBAR(); SB0(); \
  { const u32 xA0 = aA0, xA1 = aA1, xB0 = bA0, xB1 = bA1; \
    ISSUE_G1(xA0, xA1, xB0, xB1); } \
  _Pragma("unroll") \
  for (int t = 0; t < 8; t++) { \
    const u32 bo  = (u32)((t & 1) * 65536); \
    const u32 obo = (u32)(((t + 1) & 1) * 65536); \
    const u32 xA0 = aA0 + bo,  xA1 = aA1 + bo,  xB0 = bA0 + bo,  xB1 = bA1 + bo; \
    const u32 yA0 = aA0 + obo, yA1 = aA1 + obo, yB0 = bA0 + obo, yB1 = bA1 + obo; \
    LGKM0_SB(); \
    ISSUE_G2(xA0, xA1, xB0, xB1); \
    SB0(); \
    MFMA_Q(0, 0, A03, Bq); \
    LGKM8_SB(); \
    MFMA_Q(0, 2, A03, Bq2); \
    LGKM0_SB(); \
    MFMA_Q(4, 0, A47, Bq); \
    VMCNT0(); \
    SBAR(); SB0(); \
    if (t < 7) { ISSUE_G1(yA0, yA1, yB0, yB1); } \
    if (t < 6) { stTile(t & 1, t + 2); } \
    SB0(); \
    MFMA_Q(4, 2, A47, Bq2); \
  } } while (0)

// ---------------- kernel 4: sim = nn_feats @ features^T / T, fused lse + positives ----
__global__ __launch_bounds__(512, 2) void k_sim_gemm(
    const u16* __restrict__ featb, const u16* __restrict__ queueb,
    const int* __restrict__ nnidx,
    float2* __restrict__ lsep, float* __restrict__ pos) {
  __shared__ u16 lds[65536];
  const int tid = threadIdx.x;
  const int w = tid >> 6, lane = tid & 63;
  const int wr = w >> 2, wc = w & 3;
  const int li = lane & 15, lg = lane >> 4;
  const int bid = (int)blockIdx.x;
  const int wg = (bid & 7) * 32 + (bid >> 3);     // XCD swizzle (256 = 8x32)
  const int mt = wg & 15, ct = wg >> 4;
  const int brow = mt * 256, bcol = ct * 256;

  const int srw = tid >> 3;
  const int ssl = (tid & 7) ^ ((tid >> 3) & 7);
  const int ldsw = w * 512;
  const u16* pA[4]; const u16* pB[4];
  #pragma unroll
  for (int h = 0; h < 2; h++)
    #pragma unroll
    for (int l = 0; l < 2; l++) {
      pA[h*2+l] = queueb + (size_t)nnidx[brow + h*128 + l*64 + srw] * DDIM + ssl * 8;
      pB[h*2+l] = featb  + (size_t)(bcol + h*128 + l*64 + srw) * DDIM + ssl * 8;
    }

  const int sx = li & 7;
  const int u0 = (lg ^ sx) * 8;
  const int u1 = ((4 + lg) ^ sx) * 8;
  const int aBase = wr * 8192 + li * 64;
  const int bBase = 16384 + (wc >> 1) * 8192 + ((wc & 1) * 64 + li) * 64;
  const u32 aA0 = (u32)(size_t)(las_ptr)&lds[aBase + u0];
  const u32 aA1 = (u32)(size_t)(las_ptr)&lds[aBase + u1];
  const u32 bA0 = (u32)(size_t)(las_ptr)&lds[bBase + u0];
  const u32 bA1 = (u32)(size_t)(las_ptr)&lds[bBase + u1];

  f32x4_t acc[8][4] = {};

  auto stTile = [&](int b, int t) {
    #pragma unroll
    for (int h = 0; h < 2; h++)
      #pragma unroll
      for (int l = 0; l < 2; l++)
        __builtin_amdgcn_global_load_lds((gas_ptr)(pA[h*2+l] + t * 64),
            (las_ptr)&lds[b * 32768 + h * 8192 + l * 4096 + ldsw], 16, 0, 0);
    #pragma unroll
    for (int h = 0; h < 2; h++)
      #pragma unroll
      for (int l = 0; l < 2; l++)
        __builtin_amdgcn_global_load_lds((gas_ptr)(pB[h*2+l] + t * 64),
            (las_ptr)&lds[b * 32768 + 16384 + h * 8192 + l * 4096 + ldsw], 16, 0, 0);
  };

  bf16x8_t A03[8], A47[8], Bq[4], Bq2[4];

  GEMM_MAIN_LOOP();

  // epilogue: scale by 1/T=2, positives, diag mask, per-row (max, sumexp) over 64 cols
  #pragma unroll
  for (int m = 0; m < 8; m++) {
    #pragma unroll
    for (int j = 0; j < 4; j++) {
      int row = brow + wr * 128 + m * 16 + lg * 4 + j;
      float vals[4];
      float vmax = -3.0e38f;
      #pragma unroll
      for (int n = 0; n < 4; n++) {
        int col = bcol + wc * 64 + n * 16 + li;
        float v = acc[m][n][j] * 2.0f;
        if (col == (row ^ NHALF)) pos[row] = v;   // positive sample (unique writer)
        if (col == row) v = -1.0e30f;             // diag mask
        vals[n] = v;
        vmax = fmaxf(vmax, v);
      }
      float sum = 0.f;
      #pragma unroll
      for (int n = 0; n < 4; n++) sum += __expf(vals[n] - vmax);
      #pragma unroll
      for (int off = 1; off < 16; off <<= 1) {
        float mo = __shfl_xor(vmax, off);
        float so = __shfl_xor(sum, off);
        float M = fmaxf(vmax, mo);
        sum = sum * __expf(vmax - M) + so * __expf(mo - M);
        vmax = M;
      }
      if (li == 0) lsep[(size_t)row * 64 + (ct * 4 + wc)] = make_float2(vmax, sum);
    }
  }
}

// ---------------- kernel 5: per-row logsumexp merge ----------------
__global__ void k_lse(const float2* __restrict__ lsep, float* __restrict__ lse) {
  int row = (int)((blockIdx.x * blockDim.x + threadIdx.x) >> 6);
  int lane = threadIdx.x & 63;
  float2 p = lsep[(size_t)row * 64 + lane];
  float m = p.x, s = p.y;
  #pragma unroll
  for (int off = 1; off < 64; off <<= 1) {
    float mo = __shfl_xor(m, off), so = __shfl_xor(s, off);
    float M = fmaxf(m, mo);
    s = s * __expf(m - M) + so * __expf(mo - M);
    m = M;
  }
  if (lane == 0) lse[row] = m + __logf(s);
}

// ---------------- kernel 6: final scalar ----------------
__global__ void k_final(const float* __restrict__ lse, const float* __restrict__ pos,
                        float* __restrict__ out) {
  __shared__ float red[4];
  int tid = threadIdx.x;
  float a = 0.f;
  for (int i = tid; i < NFEAT; i += 256) a += lse[i] - pos[i];
  #pragma unroll
  for (int off = 32; off >= 1; off >>= 1) a += __shfl_xor(a, off);
  if ((tid & 63) == 0) red[tid >> 6] = a;
  __syncthreads();
  if (tid == 0) out[0] = (red[0] + red[1] + red[2] + red[3]) / (float)NFEAT;
}

extern "C" void kernel_launch(void* const* d_in, const int* in_sizes, int n_in,
                              void* d_out, int out_size, void* d_ws, size_t ws_size,
                              hipStream_t stream) {
  const float* zi    = (const float*)d_in[0];
  const float* zj    = (const float*)d_in[1];
  const float* queue = (const float*)d_in[2];
  float* out = (float*)d_out;
  char* ws = (char*)d_ws;

  // ws layout (bytes):
  u16*    queueb = (u16*)(ws + 0);               // 32768*512*2 = 33554432
  u16*    featb  = (u16*)(ws + 33554432);        // 4096*512*2  = 4194304
  u8*     queue8 = (u8*)(ws + 37748736);         // 32768*512   = 16777216
  u8*     feat8  = (u8*)(ws + 54525952);         // 4096*512    = 2097152
  u64*    part   = (u64*)(ws + 56623104);        // 4096*512*8  = 16777216
  int*    nnidx  = (int*)(ws + 73400320);        // 4096*4      = 16384
  float2* lsep   = (float2*)(ws + 73416704);     // 4096*64*8   = 2097152
  float*  pos    = (float*)(ws + 75513856);      // 4096*4      = 16384
  float*  lse    = (float*)(ws + 75530240);      // 4096*4      = 16384
  // total = 75546624 bytes (~72 MB)

  k_norm<<<9216, 256, 0, stream>>>(zi, zj, queue, featb, queueb, feat8, queue8);
  k_argmax_gemm8<<<4096, 512, 0, stream>>>(feat8, queue8, part);
  k_argmax_reduce<<<1024, 256, 0, stream>>>(part, nnidx);
  k_sim_gemm<<<256, 512, 0, stream>>>(featb, queueb, nnidx, lsep, pos);
  k_lse<<<1024, 256, 0, stream>>>(lsep, lse);
  k_final<<<1, 256, 0, stream>>>(lse, pos, out);
}

// Round 9
// 506.476 us; speedup vs baseline: 1.0305x; 1.0305x over previous
//
#include <hip/hip_runtime.h>
#include <cstdint>

#define NFEAT 4096
#define NHALF 2048
#define DDIM  512
#define QROWS 32768

typedef unsigned short u16;
typedef unsigned char  u8;
typedef unsigned int   u32;
typedef unsigned long long u64;

typedef __bf16 bf16x8_t __attribute__((ext_vector_type(8)));
typedef float  f32x4_t  __attribute__((ext_vector_type(4)));
typedef float  f32x16_t __attribute__((ext_vector_type(16)));
typedef int    i32x4_t  __attribute__((ext_vector_type(4)));
typedef int    i32x8_t  __attribute__((ext_vector_type(8)));

typedef const __attribute__((address_space(1))) void* gas_ptr;
typedef __attribute__((address_space(3))) void* las_ptr;

__device__ __forceinline__ u16 f2bf(float f) {
  u32 u = __float_as_uint(f);
  u32 r = u + 0x7FFFu + ((u >> 16) & 1u);
  return (u16)(r >> 16);
}

// monotonic unsigned encoding of float (no NaN/Inf expected)
__device__ __forceinline__ u32 fkey(float f) {
  u32 u = __float_as_uint(f);
  return (u & 0x80000000u) ? ~u : (u | 0x80000000u);
}

// ---------------- kernel 1: l2-normalize rows -> bf16 + fp8(e4m3) ----------------
__global__ void k_norm(const float* __restrict__ zi, const float* __restrict__ zj,
                       const float* __restrict__ queue,
                       u16* __restrict__ featb, u16* __restrict__ queueb,
                       u8* __restrict__ feat8, u8* __restrict__ queue8) {
  int gw = (int)((blockIdx.x * blockDim.x + threadIdx.x) >> 6);
  int lane = threadIdx.x & 63;
  const float* src; u16* dst; u8* dst8;
  if (gw < NFEAT) {
    src = (gw < NHALF) ? (zi + (size_t)gw * DDIM) : (zj + (size_t)(gw - NHALF) * DDIM);
    dst = featb + (size_t)gw * DDIM;
    dst8 = feat8 + (size_t)gw * DDIM;
  } else {
    int r = gw - NFEAT;
    src = queue + (size_t)r * DDIM;
    dst = queueb + (size_t)r * DDIM;
    dst8 = queue8 + (size_t)r * DDIM;
  }
  float4 v0 = reinterpret_cast<const float4*>(src)[lane * 2];
  float4 v1 = reinterpret_cast<const float4*>(src)[lane * 2 + 1];
  float ss = v0.x*v0.x + v0.y*v0.y + v0.z*v0.z + v0.w*v0.w
           + v1.x*v1.x + v1.y*v1.y + v1.z*v1.z + v1.w*v1.w;
  #pragma unroll
  for (int off = 32; off >= 1; off >>= 1) ss += __shfl_xor(ss, off);
  float inv = 1.0f / fmaxf(sqrtf(ss), 1e-12f);
  float n0 = v0.x*inv, n1 = v0.y*inv, n2 = v0.z*inv, n3 = v0.w*inv;
  float n4 = v1.x*inv, n5 = v1.y*inv, n6 = v1.z*inv, n7 = v1.w*inv;
  ushort4 o0, o1;
  o0.x = f2bf(n0); o0.y = f2bf(n1); o0.z = f2bf(n2); o0.w = f2bf(n3);
  o1.x = f2bf(n4); o1.y = f2bf(n5); o1.z = f2bf(n6); o1.w = f2bf(n7);
  reinterpret_cast<ushort4*>(dst)[lane * 2]     = o0;
  reinterpret_cast<ushort4*>(dst)[lane * 2 + 1] = o1;
  // fp8 e4m3 pack (v_cvt_pk_fp8_f32: 2 floats -> 2 bytes in low 16 bits)
  u32 p01, p23, p45, p67;
  asm("v_cvt_pk_fp8_f32 %0, %1, %2" : "=v"(p01) : "v"(n0), "v"(n1));
  asm("v_cvt_pk_fp8_f32 %0, %1, %2" : "=v"(p23) : "v"(n2), "v"(n3));
  asm("v_cvt_pk_fp8_f32 %0, %1, %2" : "=v"(p45) : "v"(n4), "v"(n5));
  asm("v_cvt_pk_fp8_f32 %0, %1, %2" : "=v"(p67) : "v"(n6), "v"(n7));
  uint2 w8;
  w8.x = (p01 & 0xFFFFu) | (p23 << 16);
  w8.y = (p45 & 0xFFFFu) | (p67 << 16);
  reinterpret_cast<uint2*>(dst8)[lane] = w8;
}

#define SB0() __builtin_amdgcn_sched_barrier(0)
#define LGKM0_SB() do { asm volatile("s_waitcnt lgkmcnt(0)" ::: "memory"); SB0(); } while (0)
#define LGKM8_SB() do { asm volatile("s_waitcnt lgkmcnt(8)" ::: "memory"); SB0(); } while (0)
#define VMCNT8() asm volatile("s_waitcnt vmcnt(8)" ::: "memory")
#define VMCNT0() asm volatile("s_waitcnt vmcnt(0)" ::: "memory")
#define SBAR() __builtin_amdgcn_s_barrier()
#define RD(dst, base, off) asm volatile("ds_read_b128 %0, %1 offset:" off \
                                        : "=v"(dst) : "v"(base))

// ---------------- kernel 2: fp8 MX GEMM features @ queue^T + fused row-argmax ----
// BM=128, BN=256, BK=64 bytes. 512 thr = 8 waves (2M x 4N), wave tile 64x64 via
// 32x32x64 f8f6f4 (2m x 2n, acc 64 regs). Scale = 1.0 (0x7F E8M0), verified R8.
// LDS tile 24KB (A 8 + B 16), dbuf 48KB -> 2 blocks/CU at launch_bounds(512,4).
// FRAGMENT-ORDERED LDS (conflict-free): slot addr = ((mb*4 + hi*2 + s)*32 + r31)*16
// holds global (row mb*32+r31, k bytes t*64 + hi*32 + s*16 .. +16). A wave's
// ds_read_b128 for fixed (mb,s) = lanes hi*1024 + r31*16 -> two contiguous 512B
// runs -> zero bank conflicts. Staged linearly: thread tid -> slot tid*16, global
// source carries the (mb,hi,s,r31) permutation (per-lane source is allowed).
// Operand ping-pong keeps <=3 i32x8 frags live -> no scratch spill (R8 lesson).
#define MFMA8(ACC, AV, BV) \
  ACC = __builtin_amdgcn_mfma_scale_f32_32x32x64_f8f6f4(AV, BV, ACC, 0, 0, 0, \
        0x7F7F7F7F, 0, 0x7F7F7F7F)

#define FP8_TILE(O0, O1, O2, O3) do { \
    i32x4_t t0, t1, t2, t3; \
    RD(t0, aAd, O0); RD(t1, aAd, O1); \
    RD(t2, bAd, O0); RD(t3, bAd, O1); \
    LGKM0_SB(); \
    i32x8_t A0 = __builtin_shufflevector(t0, t1, 0, 1, 2, 3, 4, 5, 6, 7); \
    i32x8_t B0 = __builtin_shufflevector(t2, t3, 0, 1, 2, 3, 4, 5, 6, 7); \
    RD(t0, bAd, O2); RD(t1, bAd, O3); \
    __builtin_amdgcn_s_setprio(1); \
    MFMA8(acc00, A0, B0); \
    __builtin_amdgcn_s_setprio(0); \
    LGKM0_SB(); \
    i32x8_t B1 = __builtin_shufflevector(t0, t1, 0, 1, 2, 3, 4, 5, 6, 7); \
    RD(t2, aAd, O2); RD(t3, aAd, O3); \
    __builtin_amdgcn_s_setprio(1); \
    MFMA8(acc01, A0, B1); \
    __builtin_amdgcn_s_setprio(0); \
    LGKM0_SB(); \
    i32x8_t A1 = __builtin_shufflevector(t2, t3, 0, 1, 2, 3, 4, 5, 6, 7); \
    __builtin_amdgcn_s_setprio(1); \
    MFMA8(acc10, A1, B0); \
    MFMA8(acc11, A1, B1); \
    __builtin_amdgcn_s_setprio(0); \
  } while (0)

__global__ __launch_bounds__(512, 4) void k_argmax_gemm8(
    const u8* __restrict__ feat8, const u8* __restrict__ queue8,
    u64* __restrict__ part) {
  __shared__ u8 lds[49152];
  const int tid = threadIdx.x;
  const int w = tid >> 6, lane = tid & 63;
  const int wrm = w >> 2, wcn = w & 3;
  const int l31 = lane & 31, hi = lane >> 5;
  const int bid = (int)blockIdx.x;
  const int wg = (bid & 7) * 512 + (bid >> 3);   // bijective XCD swizzle (4096 = 8x512)
  const int mt = wg & 31, qt = wg >> 5;
  const int brow = mt * 128, bcol = qt * 256;

  // staging decomposition: tid -> (mb, hi, s, r31); dest = lds + tid*16 (linear)
  const int smb = tid >> 7;
  const int soff = ((tid >> 6) & 1) * 32 + ((tid >> 5) & 1) * 16;  // shi*32 + ssl*16
  const int sr  = tid & 31;
  const u8* pA  = feat8  + (size_t)(brow + smb * 32 + sr) * DDIM + soff;
  const u8* pB0 = queue8 + (size_t)(bcol + smb * 32 + sr) * DDIM + soff;
  const u8* pB1 = pB0 + (size_t)128 * DDIM;
  const u32 dA  = (u32)(size_t)(las_ptr)&lds[tid * 16];
  const u32 dB0 = dA + 8192, dB1 = dA + 16384;

  // read-side standing addresses; mb/s/buf selected via literal offsets
  const u32 aAd = (u32)(size_t)(las_ptr)&lds[wrm * 4096 + hi * 1024 + l31 * 16];
  const u32 bAd = (u32)(size_t)(las_ptr)&lds[8192 + wcn * 4096 + hi * 1024 + l31 * 16];

  f32x16_t acc00 = {}, acc01 = {}, acc10 = {}, acc11 = {};

  auto stage = [&](int b, int t) {
    __builtin_amdgcn_global_load_lds((gas_ptr)(pA  + t * 64), (las_ptr)(size_t)(dA  + b * 24576), 16, 0, 0);
    __builtin_amdgcn_global_load_lds((gas_ptr)(pB0 + t * 64), (las_ptr)(size_t)(dB0 + b * 24576), 16, 0, 0);
    __builtin_amdgcn_global_load_lds((gas_ptr)(pB1 + t * 64), (las_ptr)(size_t)(dB1 + b * 24576), 16, 0, 0);
  };

  stage(0, 0);
  VMCNT0();
  SBAR();

  #pragma unroll
  for (int t = 0; t < 8; t++) {
    if (t < 7) stage((t + 1) & 1, t + 1);
    if ((t & 1) == 0) FP8_TILE("0", "512", "2048", "2560");
    else              FP8_TILE("24576", "25088", "26624", "27136");
    if (t < 7) { VMCNT0(); SBAR(); }
  }

  // epilogue: per-row argmax over this block's 256 cols.
  // C/D 32x32 layout: col = lane&31, row = (reg&3) + 8*(reg>>2) + 4*(lane>>5).
  const u32 c0 = (u32)(bcol + wcn * 64 + l31);
  const int rbase = brow + wrm * 64 + 4 * hi;
  const int pslot = qt * 4 + wcn;
  #pragma unroll
  for (int m = 0; m < 2; m++) {
    #pragma unroll
    for (int reg = 0; reg < 16; reg++) {
      float v0 = m == 0 ? acc00[reg] : acc10[reg];
      float v1 = m == 0 ? acc01[reg] : acc11[reg];
      u64 k0 = ((u64)fkey(v0) << 32) | (u64)(0xFFFFFFFFu - c0);
      u64 k1 = ((u64)fkey(v1) << 32) | (u64)(0xFFFFFFFFu - (c0 + 32));
      u64 best = k0 > k1 ? k0 : k1;
      #pragma unroll
      for (int off = 1; off < 32; off <<= 1) {
        u64 o = __shfl_xor(best, off);
        best = best > o ? best : o;
      }
      if (l31 == 0) {
        int row = rbase + m * 32 + (reg & 3) + 8 * (reg >> 2);
        part[(size_t)row * 512 + pslot] = best;
      }
    }
  }
}

// ---------------- kernel 3: reduce argmax partials -> nn_idx ----------------
__global__ void k_argmax_reduce(const u64* __restrict__ part, int* __restrict__ nnidx) {
  int row = (int)((blockIdx.x * blockDim.x + threadIdx.x) >> 6);
  int lane = threadIdx.x & 63;
  const u64* p = part + (size_t)row * 512;
  u64 best = 0;
  #pragma unroll
  for (int i = 0; i < 8; i++) { u64 v = p[lane * 8 + i]; best = best > v ? best : v; }
  #pragma unroll
  for (int off = 1; off < 64; off <<= 1) { u64 o = __shfl_xor(best, off); best = best > o ? best : o; }
  if (lane == 0) nnidx[row] = (int)(0xFFFFFFFFu - (u32)(best & 0xFFFFFFFFu));
}

// ---------------- bf16 pipelined GEMM pieces (k_sim_gemm, R7 structure) ----------
#define MFMA_Q(MB, NB, AF, BF) do { \
  __builtin_amdgcn_s_setprio(1); \
  _Pragma("unroll") \
  for (int kk_ = 0; kk_ < 2; kk_++) \
    _Pragma("unroll") \
    for (int m_ = 0; m_ < 4; m_++) \
      _Pragma("unroll") \
      for (int n_ = 0; n_ < 2; n_++) \
        acc[MB + m_][NB + n_] = __builtin_amdgcn_mfma_f32_16x16x32_bf16( \
            AF[m_*2+kk_], BF[n_*2+kk_], acc[MB+m_][NB+n_], 0, 0, 0); \
  __builtin_amdgcn_s_setprio(0); } while (0)

#define ISSUE_G1(XA0, XA1, XB0, XB1) do { \
  RD(Bq[0],  XB0, "0");    RD(Bq[1],  XB1, "0");    \
  RD(Bq[2],  XB0, "2048"); RD(Bq[3],  XB1, "2048"); \
  RD(A03[0], XA0, "0");    RD(A03[1], XA1, "0");    \
  RD(A03[2], XA0, "2048"); RD(A03[3], XA1, "2048"); \
  RD(A03[4], XA0, "4096"); RD(A03[5], XA1, "4096"); \
  RD(A03[6], XA0, "6144"); RD(A03[7], XA1, "6144"); } while (0)

#define ISSUE_G2(XA0, XA1, XB0, XB1) do { \
  RD(Bq2[0], XB0, "4096");  RD(Bq2[1], XB1, "4096");  \
  RD(Bq2[2], XB0, "6144");  RD(Bq2[3], XB1, "6144");  \
  RD(A47[0], XA0, "8192");  RD(A47[1], XA1, "8192");  \
  RD(A47[2], XA0, "10240"); RD(A47[3], XA1, "10240"); \
  RD(A47[4], XA0, "12288"); RD(A47[5], XA1, "12288"); \
  RD(A47[6], XA0, "14336"); RD(A47[7], XA1, "14336"); } while (0)

#define GEMM_MAIN_LOOP() do { \
  stTile(0, 0); stTile(1, 1); \
  VMCNT8(); \
  SBAR(); SB0(); \
  { const u32 xA0 = aA0, xA1 = aA1, xB0 = bA0, xB1 = bA1; \
    ISSUE_G1(xA0, xA1, xB0, xB1); } \
  _Pragma("unroll") \
  for (int t = 0; t < 8; t++) { \
    const u32 bo  = (u32)((t & 1) * 65536); \
    const u32 obo = (u32)(((t + 1) & 1) * 65536); \
    const u32 xA0 = aA0 + bo,  xA1 = aA1 + bo,  xB0 = bA0 + bo,  xB1 = bA1 + bo; \
    const u32 yA0 = aA0 + obo, yA1 = aA1 + obo, yB0 = bA0 + obo, yB1 = bA1 + obo; \
    LGKM0_SB(); \
    ISSUE_G2(xA0, xA1, xB0, xB1); \
    SB0(); \
    MFMA_Q(0, 0, A03, Bq); \
    LGKM8_SB(); \
    MFMA_Q(0, 2, A03, Bq2); \
    LGKM0_SB(); \
    MFMA_Q(4, 0, A47, Bq); \
    VMCNT0(); \
    SBAR(); SB0(); \
    if (t < 7) { ISSUE_G1(yA0, yA1, yB0, yB1); } \
    if (t < 6) { stTile(t & 1, t + 2); } \
    SB0(); \
    MFMA_Q(4, 2, A47, Bq2); \
  } } while (0)

// ---------------- kernel 4: sim = nn_feats @ features^T / T, fused lse + positives ----
__global__ __launch_bounds__(512, 2) void k_sim_gemm(
    const u16* __restrict__ featb, const u16* __restrict__ queueb,
    const int* __restrict__ nnidx,
    float2* __restrict__ lsep, float* __restrict__ pos) {
  __shared__ u16 lds[65536];
  const int tid = threadIdx.x;
  const int w = tid >> 6, lane = tid & 63;
  const int wr = w >> 2, wc = w & 3;
  const int li = lane & 15, lg = lane >> 4;
  const int bid = (int)blockIdx.x;
  const int wg = (bid & 7) * 32 + (bid >> 3);     // XCD swizzle (256 = 8x32)
  const int mt = wg & 15, ct = wg >> 4;
  const int brow = mt * 256, bcol = ct * 256;

  const int srw = tid >> 3;
  const int ssl = (tid & 7) ^ ((tid >> 3) & 7);
  const int ldsw = w * 512;
  const u16* pA[4]; const u16* pB[4];
  #pragma unroll
  for (int h = 0; h < 2; h++)
    #pragma unroll
    for (int l = 0; l < 2; l++) {
      pA[h*2+l] = queueb + (size_t)nnidx[brow + h*128 + l*64 + srw] * DDIM + ssl * 8;
      pB[h*2+l] = featb  + (size_t)(bcol + h*128 + l*64 + srw) * DDIM + ssl * 8;
    }

  const int sx = li & 7;
  const int u0 = (lg ^ sx) * 8;
  const int u1 = ((4 + lg) ^ sx) * 8;
  const int aBase = wr * 8192 + li * 64;
  const int bBase = 16384 + (wc >> 1) * 8192 + ((wc & 1) * 64 + li) * 64;
  const u32 aA0 = (u32)(size_t)(las_ptr)&lds[aBase + u0];
  const u32 aA1 = (u32)(size_t)(las_ptr)&lds[aBase + u1];
  const u32 bA0 = (u32)(size_t)(las_ptr)&lds[bBase + u0];
  const u32 bA1 = (u32)(size_t)(las_ptr)&lds[bBase + u1];

  f32x4_t acc[8][4] = {};

  auto stTile = [&](int b, int t) {
    #pragma unroll
    for (int h = 0; h < 2; h++)
      #pragma unroll
      for (int l = 0; l < 2; l++)
        __builtin_amdgcn_global_load_lds((gas_ptr)(pA[h*2+l] + t * 64),
            (las_ptr)&lds[b * 32768 + h * 8192 + l * 4096 + ldsw], 16, 0, 0);
    #pragma unroll
    for (int h = 0; h < 2; h++)
      #pragma unroll
      for (int l = 0; l < 2; l++)
        __builtin_amdgcn_global_load_lds((gas_ptr)(pB[h*2+l] + t * 64),
            (las_ptr)&lds[b * 32768 + 16384 + h * 8192 + l * 4096 + ldsw], 16, 0, 0);
  };

  bf16x8_t A03[8], A47[8], Bq[4], Bq2[4];

  GEMM_MAIN_LOOP();

  // epilogue: scale by 1/T=2, positives, diag mask, per-row (max, sumexp) over 64 cols
  #pragma unroll
  for (int m = 0; m < 8; m++) {
    #pragma unroll
    for (int j = 0; j < 4; j++) {
      int row = brow + wr * 128 + m * 16 + lg * 4 + j;
      float vals[4];
      float vmax = -3.0e38f;
      #pragma unroll
      for (int n = 0; n < 4; n++) {
        int col = bcol + wc * 64 + n * 16 + li;
        float v = acc[m][n][j] * 2.0f;
        if (col == (row ^ NHALF)) pos[row] = v;   // positive sample (unique writer)
        if (col == row) v = -1.0e30f;             // diag mask
        vals[n] = v;
        vmax = fmaxf(vmax, v);
      }
      float sum = 0.f;
      #pragma unroll
      for (int n = 0; n < 4; n++) sum += __expf(vals[n] - vmax);
      #pragma unroll
      for (int off = 1; off < 16; off <<= 1) {
        float mo = __shfl_xor(vmax, off);
        float so = __shfl_xor(sum, off);
        float M = fmaxf(vmax, mo);
        sum = sum * __expf(vmax - M) + so * __expf(mo - M);
        vmax = M;
      }
      if (li == 0) lsep[(size_t)row * 64 + (ct * 4 + wc)] = make_float2(vmax, sum);
    }
  }
}

// ---------------- kernel 5: per-row logsumexp merge ----------------
__global__ void k_lse(const float2* __restrict__ lsep, float* __restrict__ lse) {
  int row = (int)((blockIdx.x * blockDim.x + threadIdx.x) >> 6);
  int lane = threadIdx.x & 63;
  float2 p = lsep[(size_t)row * 64 + lane];
  float m = p.x, s = p.y;
  #pragma unroll
  for (int off = 1; off < 64; off <<= 1) {
    float mo = __shfl_xor(m, off), so = __shfl_xor(s, off);
    float M = fmaxf(m, mo);
    s = s * __expf(m - M) + so * __expf(mo - M);
    m = M;
  }
  if (lane == 0) lse[row] = m + __logf(s);
}

// ---------------- kernel 6: final scalar ----------------
__global__ void k_final(const float* __restrict__ lse, const float* __restrict__ pos,
                        float* __restrict__ out) {
  __shared__ float red[4];
  int tid = threadIdx.x;
  float a = 0.f;
  for (int i = tid; i < NFEAT; i += 256) a += lse[i] - pos[i];
  #pragma unroll
  for (int off = 32; off >= 1; off >>= 1) a += __shfl_xor(a, off);
  if ((tid & 63) == 0) red[tid >> 6] = a;
  __syncthreads();
  if (tid == 0) out[0] = (red[0] + red[1] + red[2] + red[3]) / (float)NFEAT;
}

extern "C" void kernel_launch(void* const* d_in, const int* in_sizes, int n_in,
                              void* d_out, int out_size, void* d_ws, size_t ws_size,
                              hipStream_t stream) {
  const float* zi    = (const float*)d_in[0];
  const float* zj    = (const float*)d_in[1];
  const float* queue = (const float*)d_in[2];
  float* out = (float*)d_out;
  char* ws = (char*)d_ws;

  // ws layout (bytes):
  u16*    queueb = (u16*)(ws + 0);               // 32768*512*2 = 33554432
  u16*    featb  = (u16*)(ws + 33554432);        // 4096*512*2  = 4194304
  u8*     queue8 = (u8*)(ws + 37748736);         // 32768*512   = 16777216
  u8*     feat8  = (u8*)(ws + 54525952);         // 4096*512    = 2097152
  u64*    part   = (u64*)(ws + 56623104);        // 4096*512*8  = 16777216
  int*    nnidx  = (int*)(ws + 73400320);        // 4096*4      = 16384
  float2* lsep   = (float2*)(ws + 73416704);     // 4096*64*8   = 2097152
  float*  pos    = (float*)(ws + 75513856);      // 4096*4      = 16384
  float*  lse    = (float*)(ws + 75530240);      // 4096*4      = 16384
  // total = 75546624 bytes (~72 MB)

  k_norm<<<9216, 256, 0, stream>>>(zi, zj, queue, featb, queueb, feat8, queue8);
  k_argmax_gemm8<<<4096, 512, 0, stream>>>(feat8, queue8, part);
  k_argmax_reduce<<<1024, 256, 0, stream>>>(part, nnidx);
  k_sim_gemm<<<256, 512, 0, stream>>>(featb, queueb, nnidx, lsep, pos);
  k_lse<<<1024, 256, 0, stream>>>(lsep, lse);
  k_final<<<1, 256, 0, stream>>>(lse, pos, out);
}

// Round 10
// 300.486 us; speedup vs baseline: 1.7370x; 1.6855x over previous
//
#include <hip/hip_runtime.h>
#include <cstdint>

#define NFEAT 4096
#define NHALF 2048
#define DDIM  512
#define QROWS 32768

typedef unsigned short u16;
typedef unsigned char  u8;
typedef unsigned int   u32;
typedef unsigned long long u64;

typedef __bf16 bf16x8_t __attribute__((ext_vector_type(8)));
typedef float  f32x4_t  __attribute__((ext_vector_type(4)));
typedef float  f32x16_t __attribute__((ext_vector_type(16)));
typedef int    i32x4_t  __attribute__((ext_vector_type(4)));
typedef int    i32x8_t  __attribute__((ext_vector_type(8)));

typedef const __attribute__((address_space(1))) void* gas_ptr;
typedef __attribute__((address_space(3))) void* las_ptr;

__device__ __forceinline__ u16 f2bf(float f) {
  u32 u = __float_as_uint(f);
  u32 r = u + 0x7FFFu + ((u >> 16) & 1u);
  return (u16)(r >> 16);
}

// monotonic unsigned encoding of float (no NaN/Inf expected)
__device__ __forceinline__ u32 fkey(float f) {
  u32 u = __float_as_uint(f);
  return (u & 0x80000000u) ? ~u : (u | 0x80000000u);
}

// ---------------- kernel 1: l2-normalize rows -> bf16 + fp8(e4m3) ----------------
__global__ void k_norm(const float* __restrict__ zi, const float* __restrict__ zj,
                       const float* __restrict__ queue,
                       u16* __restrict__ featb, u16* __restrict__ queueb,
                       u8* __restrict__ feat8, u8* __restrict__ queue8) {
  int gw = (int)((blockIdx.x * blockDim.x + threadIdx.x) >> 6);
  int lane = threadIdx.x & 63;
  const float* src; u16* dst; u8* dst8;
  if (gw < NFEAT) {
    src = (gw < NHALF) ? (zi + (size_t)gw * DDIM) : (zj + (size_t)(gw - NHALF) * DDIM);
    dst = featb + (size_t)gw * DDIM;
    dst8 = feat8 + (size_t)gw * DDIM;
  } else {
    int r = gw - NFEAT;
    src = queue + (size_t)r * DDIM;
    dst = queueb + (size_t)r * DDIM;
    dst8 = queue8 + (size_t)r * DDIM;
  }
  float4 v0 = reinterpret_cast<const float4*>(src)[lane * 2];
  float4 v1 = reinterpret_cast<const float4*>(src)[lane * 2 + 1];
  float ss = v0.x*v0.x + v0.y*v0.y + v0.z*v0.z + v0.w*v0.w
           + v1.x*v1.x + v1.y*v1.y + v1.z*v1.z + v1.w*v1.w;
  #pragma unroll
  for (int off = 32; off >= 1; off >>= 1) ss += __shfl_xor(ss, off);
  float inv = 1.0f / fmaxf(sqrtf(ss), 1e-12f);
  float n0 = v0.x*inv, n1 = v0.y*inv, n2 = v0.z*inv, n3 = v0.w*inv;
  float n4 = v1.x*inv, n5 = v1.y*inv, n6 = v1.z*inv, n7 = v1.w*inv;
  ushort4 o0, o1;
  o0.x = f2bf(n0); o0.y = f2bf(n1); o0.z = f2bf(n2); o0.w = f2bf(n3);
  o1.x = f2bf(n4); o1.y = f2bf(n5); o1.z = f2bf(n6); o1.w = f2bf(n7);
  reinterpret_cast<ushort4*>(dst)[lane * 2]     = o0;
  reinterpret_cast<ushort4*>(dst)[lane * 2 + 1] = o1;
  // fp8 e4m3 pack (v_cvt_pk_fp8_f32: 2 floats -> 2 bytes in low 16 bits)
  u32 p01, p23, p45, p67;
  asm("v_cvt_pk_fp8_f32 %0, %1, %2" : "=v"(p01) : "v"(n0), "v"(n1));
  asm("v_cvt_pk_fp8_f32 %0, %1, %2" : "=v"(p23) : "v"(n2), "v"(n3));
  asm("v_cvt_pk_fp8_f32 %0, %1, %2" : "=v"(p45) : "v"(n4), "v"(n5));
  asm("v_cvt_pk_fp8_f32 %0, %1, %2" : "=v"(p67) : "v"(n6), "v"(n7));
  uint2 w8;
  w8.x = (p01 & 0xFFFFu) | (p23 << 16);
  w8.y = (p45 & 0xFFFFu) | (p67 << 16);
  reinterpret_cast<uint2*>(dst8)[lane] = w8;
}

#define SB0() __builtin_amdgcn_sched_barrier(0)
#define LGKM0_SB() do { asm volatile("s_waitcnt lgkmcnt(0)" ::: "memory"); SB0(); } while (0)
#define LGKM8_SB() do { asm volatile("s_waitcnt lgkmcnt(8)" ::: "memory"); SB0(); } while (0)
#define VMCNT8() asm volatile("s_waitcnt vmcnt(8)" ::: "memory")
#define VMCNT4() asm volatile("s_waitcnt vmcnt(4)" ::: "memory")
#define VMCNT0() asm volatile("s_waitcnt vmcnt(0)" ::: "memory")
#define SBAR() __builtin_amdgcn_s_barrier()
#define RD(dst, base, off) asm volatile("ds_read_b128 %0, %1 offset:" off \
                                        : "=v"(dst) : "v"(base))

// ---------------- kernel 2: fp8 MX GEMM features @ queue^T + fused row-argmax ----
// R10 re-shape of the R9-verified kernel (math/layout/epilogue identical, all
// refcheck'd absmax 0.0): block = 4 waves / 256 thr, tile 128x128, wave 64x64
// (2m x 2n of 32x32x64 f8f6f4, acc 64 regs). __launch_bounds__(256,2) -> 256
// unified regs/wave: acc 64 + ~50 live = no scratch (R8/R9 spill fix).
// FRAGMENT-ORDERED LDS (conflict-free, verified R9): 16B slot L = mb*128 +
// hi*64 + s*32 + r31 holds global (row mb*32+r31, kbytes hi*32+s*16). A 8KB +
// B 8KB = 16KB/tile; 3-deep ring = 48KB -> 3 blocks/CU (LDS-limited); cross-
// block overlap hides the per-tile barrier. Prefetch ledger: stage t+2 during
// tile t (buf (t+2)%3 = (t-1)%3, all reads of t-1 lgkm-confirmed before the
// t-1 boundary barrier -> WAR safe); boundary vmcnt(4) leaves stage(t+2) in
// flight and proves stage(t+1) landed; t=6 boundary vmcnt(0); prologue
// stage(0)+stage(1) then vmcnt(4).
#define MFMA8(ACC, AV, BV) \
  ACC = __builtin_amdgcn_mfma_scale_f32_32x32x64_f8f6f4(AV, BV, ACC, 0, 0, 0, \
        0x7F7F7F7F, 0, 0x7F7F7F7F)

#define FP8_TILE(XA, XB) do { \
    i32x4_t t0, t1, t2, t3; \
    RD(t0, XA, "0"); RD(t1, XA, "512"); \
    RD(t2, XB, "0"); RD(t3, XB, "512"); \
    LGKM0_SB(); \
    i32x8_t A0 = __builtin_shufflevector(t0, t1, 0, 1, 2, 3, 4, 5, 6, 7); \
    i32x8_t B0 = __builtin_shufflevector(t2, t3, 0, 1, 2, 3, 4, 5, 6, 7); \
    RD(t0, XB, "2048"); RD(t1, XB, "2560"); \
    __builtin_amdgcn_s_setprio(1); \
    MFMA8(acc00, A0, B0); \
    __builtin_amdgcn_s_setprio(0); \
    LGKM0_SB(); \
    i32x8_t B1 = __builtin_shufflevector(t0, t1, 0, 1, 2, 3, 4, 5, 6, 7); \
    RD(t2, XA, "2048"); RD(t3, XA, "2560"); \
    __builtin_amdgcn_s_setprio(1); \
    MFMA8(acc01, A0, B1); \
    __builtin_amdgcn_s_setprio(0); \
    LGKM0_SB(); \
    i32x8_t A1 = __builtin_shufflevector(t2, t3, 0, 1, 2, 3, 4, 5, 6, 7); \
    __builtin_amdgcn_s_setprio(1); \
    MFMA8(acc10, A1, B0); \
    MFMA8(acc11, A1, B1); \
    __builtin_amdgcn_s_setprio(0); \
  } while (0)

__global__ __launch_bounds__(256, 2) void k_argmax_gemm8(
    const u8* __restrict__ feat8, const u8* __restrict__ queue8,
    u64* __restrict__ part) {
  __shared__ u8 lds[49152];
  const int tid = threadIdx.x;
  const int w = tid >> 6, lane = tid & 63;
  const int wr = w >> 1, wc = w & 1;
  const int l31 = lane & 31, hi = lane >> 5;
  const int bid = (int)blockIdx.x;
  const int wg = (bid & 7) * 1024 + (bid >> 3);  // bijective XCD swizzle (8192 = 8x1024)
  const int mt = wg & 31, qt = wg >> 5;
  const int brow = mt * 128, bcol = qt * 128;

  // staging decomposition: slot L = tid (+256): mb=L>>7, shi=(L>>6)&1, ssl=(L>>5)&1, r=L&31
  const int smb = tid >> 7;                       // 0..1; second half adds +2
  const int soff = ((tid >> 6) & 1) * 32 + ((tid >> 5) & 1) * 16;
  const int sr  = tid & 31;
  const u8* pA0 = feat8  + (size_t)(brow + smb * 32 + sr) * DDIM + soff;
  const u8* pA1 = pA0 + (size_t)64 * DDIM;        // mb + 2
  const u8* pB0 = queue8 + (size_t)(bcol + smb * 32 + sr) * DDIM + soff;
  const u8* pB1 = pB0 + (size_t)64 * DDIM;
  const u32 dA = (u32)(size_t)(las_ptr)&lds[tid * 16];
  const u32 dB = dA + 8192;

  // read-side standing addresses; m/n/s/buf via literal offsets (m*2048 + s*512)
  const u32 aAd = (u32)(size_t)(las_ptr)&lds[wr * 4096 + hi * 1024 + l31 * 16];
  const u32 bAd = (u32)(size_t)(las_ptr)&lds[8192 + wc * 4096 + hi * 1024 + l31 * 16];

  f32x16_t acc00 = {}, acc01 = {}, acc10 = {}, acc11 = {};

  auto stage = [&](int b, int t) {
    const u32 base = (u32)(b * 16384);
    __builtin_amdgcn_global_load_lds((gas_ptr)(pA0 + t * 64), (las_ptr)(size_t)(dA + base), 16, 0, 0);
    __builtin_amdgcn_global_load_lds((gas_ptr)(pA1 + t * 64), (las_ptr)(size_t)(dA + base + 4096), 16, 0, 0);
    __builtin_amdgcn_global_load_lds((gas_ptr)(pB0 + t * 64), (las_ptr)(size_t)(dB + base), 16, 0, 0);
    __builtin_amdgcn_global_load_lds((gas_ptr)(pB1 + t * 64), (las_ptr)(size_t)(dB + base + 4096), 16, 0, 0);
  };

  stage(0, 0); stage(1, 1);
  VMCNT4();
  SBAR();

  #pragma unroll
  for (int t = 0; t < 8; t++) {
    if (t <= 5) stage((t + 2) % 3, t + 2);
    const u32 bb = (u32)((t % 3) * 16384);
    FP8_TILE(aAd + bb, bAd + bb);
    if (t < 7) {
      if (t <= 5) VMCNT4(); else VMCNT0();
      SBAR();
    }
  }

  // epilogue: per-row argmax over this block's 128 cols.
  // C/D 32x32 layout: col = lane&31, row = (reg&3) + 8*(reg>>2) + 4*(lane>>5).
  const u32 c0 = (u32)(bcol + wc * 64 + l31);
  const int rbase = brow + wr * 64 + 4 * hi;
  const int pslot = qt * 2 + wc;
  #pragma unroll
  for (int m = 0; m < 2; m++) {
    #pragma unroll
    for (int reg = 0; reg < 16; reg++) {
      float v0 = m == 0 ? acc00[reg] : acc10[reg];
      float v1 = m == 0 ? acc01[reg] : acc11[reg];
      u64 k0 = ((u64)fkey(v0) << 32) | (u64)(0xFFFFFFFFu - c0);
      u64 k1 = ((u64)fkey(v1) << 32) | (u64)(0xFFFFFFFFu - (c0 + 32));
      u64 best = k0 > k1 ? k0 : k1;
      #pragma unroll
      for (int off = 1; off < 32; off <<= 1) {
        u64 o = __shfl_xor(best, off);
        best = best > o ? best : o;
      }
      if (l31 == 0) {
        int row = rbase + m * 32 + (reg & 3) + 8 * (reg >> 2);
        part[(size_t)row * 512 + pslot] = best;
      }
    }
  }
}

// ---------------- kernel 3: reduce argmax partials -> nn_idx ----------------
__global__ void k_argmax_reduce(const u64* __restrict__ part, int* __restrict__ nnidx) {
  int row = (int)((blockIdx.x * blockDim.x + threadIdx.x) >> 6);
  int lane = threadIdx.x & 63;
  const u64* p = part + (size_t)row * 512;
  u64 best = 0;
  #pragma unroll
  for (int i = 0; i < 8; i++) { u64 v = p[lane * 8 + i]; best = best > v ? best : v; }
  #pragma unroll
  for (int off = 1; off < 64; off <<= 1) { u64 o = __shfl_xor(best, off); best = best > o ? best : o; }
  if (lane == 0) nnidx[row] = (int)(0xFFFFFFFFu - (u32)(best & 0xFFFFFFFFu));
}

// ---------------- bf16 pipelined GEMM pieces (k_sim_gemm, R7 structure) ----------
#define MFMA_Q(MB, NB, AF, BF) do { \
  __builtin_amdgcn_s_setprio(1); \
  _Pragma("unroll") \
  for (int kk_ = 0; kk_ < 2; kk_++) \
    _Pragma("unroll") \
    for (int m_ = 0; m_ < 4; m_++) \
      _Pragma("unroll") \
      for (int n_ = 0; n_ < 2; n_++) \
        acc[MB + m_][NB + n_] = __builtin_amdgcn_mfma_f32_16x16x32_bf16( \
            AF[m_*2+kk_], BF[n_*2+kk_], acc[MB+m_][NB+n_], 0, 0, 0); \
  __builtin_amdgcn_s_setprio(0); } while (0)

#define ISSUE_G1(XA0, XA1, XB0, XB1) do { \
  RD(Bq[0],  XB0, "0");    RD(Bq[1],  XB1, "0");    \
  RD(Bq[2],  XB0, "2048"); RD(Bq[3],  XB1, "2048"); \
  RD(A03[0], XA0, "0");    RD(A03[1], XA1, "0");    \
  RD(A03[2], XA0, "2048"); RD(A03[3], XA1, "2048"); \
  RD(A03[4], XA0, "4096"); RD(A03[5], XA1, "4096"); \
  RD(A03[6], XA0, "6144"); RD(A03[7], XA1, "6144"); } while (0)

#define ISSUE_G2(XA0, XA1, XB0, XB1) do { \
  RD(Bq2[0], XB0, "4096");  RD(Bq2[1], XB1, "4096");  \
  RD(Bq2[2], XB0, "6144");  RD(Bq2[3], XB1, "6144");  \
  RD(A47[0], XA0, "8192");  RD(A47[1], XA1, "8192");  \
  RD(A47[2], XA0, "10240"); RD(A47[3], XA1, "10240"); \
  RD(A47[4], XA0, "12288"); RD(A47[5], XA1, "12288"); \
  RD(A47[6], XA0, "14336"); RD(A47[7], XA1, "14336"); } while (0)

#define GEMM_MAIN_LOOP() do { \
  stTile(0, 0); stTile(1, 1); \
  VMCNT8(); \
  SBAR(); SB0(); \
  { const u32 xA0 = aA0, xA1 = aA1, xB0 = bA0, xB1 = bA1; \
    ISSUE_G1(xA0, xA1, xB0, xB1); } \
  _Pragma("unroll") \
  for (int t = 0; t < 8; t++) { \
    const u32 bo  = (u32)((t & 1) * 65536); \
    const u32 obo = (u32)(((t + 1) & 1) * 65536); \
    const u32 xA0 = aA0 + bo,  xA1 = aA1 + bo,  xB0 = bA0 + bo,  xB1 = bA1 + bo; \
    const u32 yA0 = aA0 + obo, yA1 = aA1 + obo, yB0 = bA0 + obo, yB1 = bA1 + obo; \
    LGKM0_SB(); \
    ISSUE_G2(xA0, xA1, xB0, xB1); \
    SB0(); \
    MFMA_Q(0, 0, A03, Bq); \
    LGKM8_SB(); \
    MFMA_Q(0, 2, A03, Bq2); \
    LGKM0_SB(); \
    MFMA_Q(4, 0, A47, Bq); \
    VMCNT0(); \
    SBAR(); SB0(); \
    if (t < 7) { ISSUE_G1(yA0, yA1, yB0, yB1); } \
    if (t < 6) { stTile(t & 1, t + 2); } \
    SB0(); \
    MFMA_Q(4, 2, A47, Bq2); \
  } } while (0)

// ---------------- kernel 4: sim = nn_feats @ features^T / T, fused lse + positives ----
__global__ __launch_bounds__(512, 2) void k_sim_gemm(
    const u16* __restrict__ featb, const u16* __restrict__ queueb,
    const int* __restrict__ nnidx,
    float2* __restrict__ lsep, float* __restrict__ pos) {
  __shared__ u16 lds[65536];
  const int tid = threadIdx.x;
  const int w = tid >> 6, lane = tid & 63;
  const int wr = w >> 2, wc = w & 3;
  const int li = lane & 15, lg = lane >> 4;
  const int bid = (int)blockIdx.x;
  const int wg = (bid & 7) * 32 + (bid >> 3);     // XCD swizzle (256 = 8x32)
  const int mt = wg & 15, ct = wg >> 4;
  const int brow = mt * 256, bcol = ct * 256;

  const int srw = tid >> 3;
  const int ssl = (tid & 7) ^ ((tid >> 3) & 7);
  const int ldsw = w * 512;
  const u16* pA[4]; const u16* pB[4];
  #pragma unroll
  for (int h = 0; h < 2; h++)
    #pragma unroll
    for (int l = 0; l < 2; l++) {
      pA[h*2+l] = queueb + (size_t)nnidx[brow + h*128 + l*64 + srw] * DDIM + ssl * 8;
      pB[h*2+l] = featb  + (size_t)(bcol + h*128 + l*64 + srw) * DDIM + ssl * 8;
    }

  const int sx = li & 7;
  const int u0 = (lg ^ sx) * 8;
  const int u1 = ((4 + lg) ^ sx) * 8;
  const int aBase = wr * 8192 + li * 64;
  const int bBase = 16384 + (wc >> 1) * 8192 + ((wc & 1) * 64 + li) * 64;
  const u32 aA0 = (u32)(size_t)(las_ptr)&lds[aBase + u0];
  const u32 aA1 = (u32)(size_t)(las_ptr)&lds[aBase + u1];
  const u32 bA0 = (u32)(size_t)(las_ptr)&lds[bBase + u0];
  const u32 bA1 = (u32)(size_t)(las_ptr)&lds[bBase + u1];

  f32x4_t acc[8][4] = {};

  auto stTile = [&](int b, int t) {
    #pragma unroll
    for (int h = 0; h < 2; h++)
      #pragma unroll
      for (int l = 0; l < 2; l++)
        __builtin_amdgcn_global_load_lds((gas_ptr)(pA[h*2+l] + t * 64),
            (las_ptr)&lds[b * 32768 + h * 8192 + l * 4096 + ldsw], 16, 0, 0);
    #pragma unroll
    for (int h = 0; h < 2; h++)
      #pragma unroll
      for (int l = 0; l < 2; l++)
        __builtin_amdgcn_global_load_lds((gas_ptr)(pB[h*2+l] + t * 64),
            (las_ptr)&lds[b * 32768 + 16384 + h * 8192 + l * 4096 + ldsw], 16, 0, 0);
  };

  bf16x8_t A03[8], A47[8], Bq[4], Bq2[4];

  GEMM_MAIN_LOOP();

  // epilogue: scale by 1/T=2, positives, diag mask, per-row (max, sumexp) over 64 cols
  #pragma unroll
  for (int m = 0; m < 8; m++) {
    #pragma unroll
    for (int j = 0; j < 4; j++) {
      int row = brow + wr * 128 + m * 16 + lg * 4 + j;
      float vals[4];
      float vmax = -3.0e38f;
      #pragma unroll
      for (int n = 0; n < 4; n++) {
        int col = bcol + wc * 64 + n * 16 + li;
        float v = acc[m][n][j] * 2.0f;
        if (col == (row ^ NHALF)) pos[row] = v;   // positive sample (unique writer)
        if (col == row) v = -1.0e30f;             // diag mask
        vals[n] = v;
        vmax = fmaxf(vmax, v);
      }
      float sum = 0.f;
      #pragma unroll
      for (int n = 0; n < 4; n++) sum += __expf(vals[n] - vmax);
      #pragma unroll
      for (int off = 1; off < 16; off <<= 1) {
        float mo = __shfl_xor(vmax, off);
        float so = __shfl_xor(sum, off);
        float M = fmaxf(vmax, mo);
        sum = sum * __expf(vmax - M) + so * __expf(mo - M);
        vmax = M;
      }
      if (li == 0) lsep[(size_t)row * 64 + (ct * 4 + wc)] = make_float2(vmax, sum);
    }
  }
}

// ---------------- kernel 5: per-row logsumexp merge ----------------
__global__ void k_lse(const float2* __restrict__ lsep, float* __restrict__ lse) {
  int row = (int)((blockIdx.x * blockDim.x + threadIdx.x) >> 6);
  int lane = threadIdx.x & 63;
  float2 p = lsep[(size_t)row * 64 + lane];
  float m = p.x, s = p.y;
  #pragma unroll
  for (int off = 1; off < 64; off <<= 1) {
    float mo = __shfl_xor(m, off), so = __shfl_xor(s, off);
    float M = fmaxf(m, mo);
    s = s * __expf(m - M) + so * __expf(mo - M);
    m = M;
  }
  if (lane == 0) lse[row] = m + __logf(s);
}

// ---------------- kernel 6: final scalar ----------------
__global__ void k_final(const float* __restrict__ lse, const float* __restrict__ pos,
                        float* __restrict__ out) {
  __shared__ float red[4];
  int tid = threadIdx.x;
  float a = 0.f;
  for (int i = tid; i < NFEAT; i += 256) a += lse[i] - pos[i];
  #pragma unroll
  for (int off = 32; off >= 1; off >>= 1) a += __shfl_xor(a, off);
  if ((tid & 63) == 0) red[tid >> 6] = a;
  __syncthreads();
  if (tid == 0) out[0] = (red[0] + red[1] + red[2] + red[3]) / (float)NFEAT;
}

extern "C" void kernel_launch(void* const* d_in, const int* in_sizes, int n_in,
                              void* d_out, int out_size, void* d_ws, size_t ws_size,
                              hipStream_t stream) {
  const float* zi    = (const float*)d_in[0];
  const float* zj    = (const float*)d_in[1];
  const float* queue = (const float*)d_in[2];
  float* out = (float*)d_out;
  char* ws = (char*)d_ws;

  // ws layout (bytes):
  u16*    queueb = (u16*)(ws + 0);               // 32768*512*2 = 33554432
  u16*    featb  = (u16*)(ws + 33554432);        // 4096*512*2  = 4194304
  u8*     queue8 = (u8*)(ws + 37748736);         // 32768*512   = 16777216
  u8*     feat8  = (u8*)(ws + 54525952);         // 4096*512    = 2097152
  u64*    part   = (u64*)(ws + 56623104);        // 4096*512*8  = 16777216
  int*    nnidx  = (int*)(ws + 73400320);        // 4096*4      = 16384
  float2* lsep   = (float2*)(ws + 73416704);     // 4096*64*8   = 2097152
  float*  pos    = (float*)(ws + 75513856);      // 4096*4      = 16384
  float*  lse    = (float*)(ws + 75530240);      // 4096*4      = 16384
  // total = 75546624 bytes (~72 MB)

  k_norm<<<9216, 256, 0, stream>>>(zi, zj, queue, featb, queueb, feat8, queue8);
  k_argmax_gemm8<<<8192, 256, 0, stream>>>(feat8, queue8, part);
  k_argmax_reduce<<<1024, 256, 0, stream>>>(part, nnidx);
  k_sim_gemm<<<256, 512, 0, stream>>>(featb, queueb, nnidx, lsep, pos);
  k_lse<<<1024, 256, 0, stream>>>(lsep, lse);
  k_final<<<1, 256, 0, stream>>>(lse, pos, out);
}

// Round 11
// 290.420 us; speedup vs baseline: 1.7972x; 1.0347x over previous
//
#include <hip/hip_runtime.h>
#include <cstdint>

#define NFEAT 4096
#define NHALF 2048
#define DDIM  512
#define QROWS 32768

typedef unsigned short u16;
typedef unsigned char  u8;
typedef unsigned int   u32;
typedef unsigned long long u64;

typedef __bf16 bf16x8_t __attribute__((ext_vector_type(8)));
typedef float  f32x4_t  __attribute__((ext_vector_type(4)));
typedef float  f32x16_t __attribute__((ext_vector_type(16)));
typedef int    i32x4_t  __attribute__((ext_vector_type(4)));
typedef int    i32x8_t  __attribute__((ext_vector_type(8)));

typedef const __attribute__((address_space(1))) void* gas_ptr;
typedef __attribute__((address_space(3))) void* las_ptr;

__device__ __forceinline__ u16 f2bf(float f) {
  u32 u = __float_as_uint(f);
  u32 r = u + 0x7FFFu + ((u >> 16) & 1u);
  return (u16)(r >> 16);
}

// monotonic unsigned encoding of float (no NaN/Inf expected)
__device__ __forceinline__ u32 fkey(float f) {
  u32 u = __float_as_uint(f);
  return (u & 0x80000000u) ? ~u : (u | 0x80000000u);
}

// ---------------- kernel 1: l2-normalize rows -> bf16 + TILED fp8(e4m3) -------
// fp8 buffers are stored PRE-TILED in the GEMM's fragment order so the GEMM's
// global_load_lds staging is fully contiguous (R10 fix: 512B-stride gather was
// 4x L2 sector amplification). Layout: addr(row,k) = (row>>5)*16384 +
// (k>>6)*2048 + ((k>>5)&1)*1024 + ((k>>4)&1)*512 + (row&31)*16 + (k&15).
__global__ void k_norm(const float* __restrict__ zi, const float* __restrict__ zj,
                       const float* __restrict__ queue,
                       u16* __restrict__ featb, u16* __restrict__ queueb,
                       u8* __restrict__ feat8T, u8* __restrict__ queue8T) {
  int gw = (int)((blockIdx.x * blockDim.x + threadIdx.x) >> 6);
  int lane = threadIdx.x & 63;
  const float* src; u16* dst; u8* dstT; int r31;
  if (gw < NFEAT) {
    src = (gw < NHALF) ? (zi + (size_t)gw * DDIM) : (zj + (size_t)(gw - NHALF) * DDIM);
    dst = featb + (size_t)gw * DDIM;
    dstT = feat8T + (size_t)(gw >> 5) * 16384; r31 = gw & 31;
  } else {
    int r = gw - NFEAT;
    src = queue + (size_t)r * DDIM;
    dst = queueb + (size_t)r * DDIM;
    dstT = queue8T + (size_t)(r >> 5) * 16384; r31 = r & 31;
  }
  float4 v0 = reinterpret_cast<const float4*>(src)[lane * 2];
  float4 v1 = reinterpret_cast<const float4*>(src)[lane * 2 + 1];
  float ss = v0.x*v0.x + v0.y*v0.y + v0.z*v0.z + v0.w*v0.w
           + v1.x*v1.x + v1.y*v1.y + v1.z*v1.z + v1.w*v1.w;
  #pragma unroll
  for (int off = 32; off >= 1; off >>= 1) ss += __shfl_xor(ss, off);
  float inv = 1.0f / fmaxf(sqrtf(ss), 1e-12f);
  float n0 = v0.x*inv, n1 = v0.y*inv, n2 = v0.z*inv, n3 = v0.w*inv;
  float n4 = v1.x*inv, n5 = v1.y*inv, n6 = v1.z*inv, n7 = v1.w*inv;
  ushort4 o0, o1;
  o0.x = f2bf(n0); o0.y = f2bf(n1); o0.z = f2bf(n2); o0.w = f2bf(n3);
  o1.x = f2bf(n4); o1.y = f2bf(n5); o1.z = f2bf(n6); o1.w = f2bf(n7);
  reinterpret_cast<ushort4*>(dst)[lane * 2]     = o0;
  reinterpret_cast<ushort4*>(dst)[lane * 2 + 1] = o1;
  // fp8 e4m3 pack (v_cvt_pk_fp8_f32: 2 floats -> 2 bytes in low 16 bits)
  u32 p01, p23, p45, p67;
  asm("v_cvt_pk_fp8_f32 %0, %1, %2" : "=v"(p01) : "v"(n0), "v"(n1));
  asm("v_cvt_pk_fp8_f32 %0, %1, %2" : "=v"(p23) : "v"(n2), "v"(n3));
  asm("v_cvt_pk_fp8_f32 %0, %1, %2" : "=v"(p45) : "v"(n4), "v"(n5));
  asm("v_cvt_pk_fp8_f32 %0, %1, %2" : "=v"(p67) : "v"(n6), "v"(n7));
  uint2 w8;
  w8.x = (p01 & 0xFFFFu) | (p23 << 16);
  w8.y = (p45 & 0xFFFFu) | (p67 << 16);
  // lane covers kbytes lane*8..+7: kt=lane>>3, hi=(lane>>2)&1, s=(lane>>1)&1, lo=(lane&1)*8
  size_t toff = (size_t)(lane >> 3) * 2048 + ((lane >> 2) & 1) * 1024
              + ((lane >> 1) & 1) * 512 + r31 * 16 + (lane & 1) * 8;
  *reinterpret_cast<uint2*>(dstT + toff) = w8;
}

#define SB0() __builtin_amdgcn_sched_barrier(0)
#define LGKM0_SB() do { asm volatile("s_waitcnt lgkmcnt(0)" ::: "memory"); SB0(); } while (0)
#define LGKM8_SB() do { asm volatile("s_waitcnt lgkmcnt(8)" ::: "memory"); SB0(); } while (0)
#define VMCNT8() asm volatile("s_waitcnt vmcnt(8)" ::: "memory")
#define VMCNT4() asm volatile("s_waitcnt vmcnt(4)" ::: "memory")
#define VMCNT0() asm volatile("s_waitcnt vmcnt(0)" ::: "memory")
#define SBAR() __builtin_amdgcn_s_barrier()
#define RD(dst, base, off) asm volatile("ds_read_b128 %0, %1 offset:" off \
                                        : "=v"(dst) : "v"(base))

// ---------------- kernel 2: fp8 MX GEMM features @ queue^T + fused row-argmax ----
// R11 = R10 (verified absmax 0.0) with (a) contiguous staging from the pre-tiled
// global buffers, (b) all-8-reads -> one lgkm0 -> 4-MFMA burst per tile.
// Block 4 waves/256 thr, tile 128x128, wave 64x64 (2m x 2n 32x32x64 f8f6f4,
// acc 64 regs). FRAGMENT-ORDERED LDS slot L = mb*128 + hi*64 + s*32 + r31
// (conflict-free reads, verified). Tile 16KB, ring-3 = 48KB -> 3 blocks/CU.
// Ledger (verified R10): stage t+2 during t into buf (t+2)%3 = (t-1)%3 (reads
// of t-1 lgkm-confirmed before its boundary barrier -> WAR safe); boundary
// vmcnt(4) proves stage(t+1) landed; t=6 boundary vmcnt(0).
#define MFMA8(ACC, AV, BV) \
  ACC = __builtin_amdgcn_mfma_scale_f32_32x32x64_f8f6f4(AV, BV, ACC, 0, 0, 0, \
        0x7F7F7F7F, 0, 0x7F7F7F7F)

#define FP8_TILE(XA, XB) do { \
    i32x4_t a00, a01, a10, a11, b00, b01, b10, b11; \
    RD(a00, XA, "0"); RD(a01, XA, "512"); \
    RD(a10, XA, "2048"); RD(a11, XA, "2560"); \
    RD(b00, XB, "0"); RD(b01, XB, "512"); \
    RD(b10, XB, "2048"); RD(b11, XB, "2560"); \
    LGKM0_SB(); \
    i32x8_t A0 = __builtin_shufflevector(a00, a01, 0, 1, 2, 3, 4, 5, 6, 7); \
    i32x8_t A1 = __builtin_shufflevector(a10, a11, 0, 1, 2, 3, 4, 5, 6, 7); \
    i32x8_t B0 = __builtin_shufflevector(b00, b01, 0, 1, 2, 3, 4, 5, 6, 7); \
    i32x8_t B1 = __builtin_shufflevector(b10, b11, 0, 1, 2, 3, 4, 5, 6, 7); \
    __builtin_amdgcn_s_setprio(1); \
    MFMA8(acc00, A0, B0); \
    MFMA8(acc01, A0, B1); \
    MFMA8(acc10, A1, B0); \
    MFMA8(acc11, A1, B1); \
    __builtin_amdgcn_s_setprio(0); \
  } while (0)

__global__ __launch_bounds__(256, 2) void k_argmax_gemm8(
    const u8* __restrict__ feat8T, const u8* __restrict__ queue8T,
    u64* __restrict__ part) {
  __shared__ u8 lds[49152];
  const int tid = threadIdx.x;
  const int w = tid >> 6, lane = tid & 63;
  const int wr = w >> 1, wc = w & 1;
  const int l31 = lane & 31, hi = lane >> 5;
  const int bid = (int)blockIdx.x;
  const int wg = (bid & 7) * 1024 + (bid >> 3);  // bijective XCD swizzle (8192 = 8x1024)
  const int mt = wg & 31, qt = wg >> 5;
  const int brow = mt * 128, bcol = qt * 128;

  // contiguous staging: thread tid covers LDS slots tid and tid+256 of each operand
  const u8* pA = feat8T  + (size_t)(brow >> 5) * 16384 + (tid >> 7) * 16384 + (tid & 127) * 16;
  const u8* pB = queue8T + (size_t)(bcol >> 5) * 16384 + (tid >> 7) * 16384 + (tid & 127) * 16;
  const u32 dA = (u32)(size_t)(las_ptr)&lds[tid * 16];
  const u32 dB = dA + 8192;

  // read-side standing addresses; m/n/s/buf via literal offsets
  const u32 aAd = (u32)(size_t)(las_ptr)&lds[wr * 4096 + hi * 1024 + l31 * 16];
  const u32 bAd = (u32)(size_t)(las_ptr)&lds[8192 + wc * 4096 + hi * 1024 + l31 * 16];

  f32x16_t acc00 = {}, acc01 = {}, acc10 = {}, acc11 = {};

  auto stage = [&](int b, int t) {
    const u32 base = (u32)(b * 16384);
    __builtin_amdgcn_global_load_lds((gas_ptr)(pA + t * 2048),         (las_ptr)(size_t)(dA + base), 16, 0, 0);
    __builtin_amdgcn_global_load_lds((gas_ptr)(pA + 32768 + t * 2048), (las_ptr)(size_t)(dA + base + 4096), 16, 0, 0);
    __builtin_amdgcn_global_load_lds((gas_ptr)(pB + t * 2048),         (las_ptr)(size_t)(dB + base), 16, 0, 0);
    __builtin_amdgcn_global_load_lds((gas_ptr)(pB + 32768 + t * 2048), (las_ptr)(size_t)(dB + base + 4096), 16, 0, 0);
  };

  stage(0, 0); stage(1, 1);
  VMCNT4();
  SBAR();

  #pragma unroll
  for (int t = 0; t < 8; t++) {
    if (t <= 5) stage((t + 2) % 3, t + 2);
    const u32 bb = (u32)((t % 3) * 16384);
    FP8_TILE(aAd + bb, bAd + bb);
    if (t < 7) {
      if (t <= 5) VMCNT4(); else VMCNT0();
      SBAR();
    }
  }

  // epilogue: per-row argmax over this block's 128 cols.
  // C/D 32x32 layout: col = lane&31, row = (reg&3) + 8*(reg>>2) + 4*(lane>>5).
  const u32 c0 = (u32)(bcol + wc * 64 + l31);
  const int rbase = brow + wr * 64 + 4 * hi;
  const int pslot = qt * 2 + wc;
  #pragma unroll
  for (int m = 0; m < 2; m++) {
    #pragma unroll
    for (int reg = 0; reg < 16; reg++) {
      float v0 = m == 0 ? acc00[reg] : acc10[reg];
      float v1 = m == 0 ? acc01[reg] : acc11[reg];
      u64 k0 = ((u64)fkey(v0) << 32) | (u64)(0xFFFFFFFFu - c0);
      u64 k1 = ((u64)fkey(v1) << 32) | (u64)(0xFFFFFFFFu - (c0 + 32));
      u64 best = k0 > k1 ? k0 : k1;
      #pragma unroll
      for (int off = 1; off < 32; off <<= 1) {
        u64 o = __shfl_xor(best, off);
        best = best > o ? best : o;
      }
      if (l31 == 0) {
        int row = rbase + m * 32 + (reg & 3) + 8 * (reg >> 2);
        part[(size_t)row * 512 + pslot] = best;
      }
    }
  }
}

// ---------------- kernel 3: reduce argmax partials -> nn_idx ----------------
__global__ void k_argmax_reduce(const u64* __restrict__ part, int* __restrict__ nnidx) {
  int row = (int)((blockIdx.x * blockDim.x + threadIdx.x) >> 6);
  int lane = threadIdx.x & 63;
  const u64* p = part + (size_t)row * 512;
  u64 best = 0;
  #pragma unroll
  for (int i = 0; i < 8; i++) { u64 v = p[lane * 8 + i]; best = best > v ? best : v; }
  #pragma unroll
  for (int off = 1; off < 64; off <<= 1) { u64 o = __shfl_xor(best, off); best = best > o ? best : o; }
  if (lane == 0) nnidx[row] = (int)(0xFFFFFFFFu - (u32)(best & 0xFFFFFFFFu));
}

// ---------------- bf16 pipelined GEMM pieces (k_sim_gemm, R7 structure) ----------
#define MFMA_Q(MB, NB, AF, BF) do { \
  __builtin_amdgcn_s_setprio(1); \
  _Pragma("unroll") \
  for (int kk_ = 0; kk_ < 2; kk_++) \
    _Pragma("unroll") \
    for (int m_ = 0; m_ < 4; m_++) \
      _Pragma("unroll") \
      for (int n_ = 0; n_ < 2; n_++) \
        acc[MB + m_][NB + n_] = __builtin_amdgcn_mfma_f32_16x16x32_bf16( \
            AF[m_*2+kk_], BF[n_*2+kk_], acc[MB+m_][NB+n_], 0, 0, 0); \
  __builtin_amdgcn_s_setprio(0); } while (0)

#define ISSUE_G1(XA0, XA1, XB0, XB1) do { \
  RD(Bq[0],  XB0, "0");    RD(Bq[1],  XB1, "0");    \
  RD(Bq[2],  XB0, "2048"); RD(Bq[3],  XB1, "2048"); \
  RD(A03[0], XA0, "0");    RD(A03[1], XA1, "0");    \
  RD(A03[2], XA0, "2048"); RD(A03[3], XA1, "2048"); \
  RD(A03[4], XA0, "4096"); RD(A03[5], XA1, "4096"); \
  RD(A03[6], XA0, "6144"); RD(A03[7], XA1, "6144"); } while (0)

#define ISSUE_G2(XA0, XA1, XB0, XB1) do { \
  RD(Bq2[0], XB0, "4096");  RD(Bq2[1], XB1, "4096");  \
  RD(Bq2[2], XB0, "6144");  RD(Bq2[3], XB1, "6144");  \
  RD(A47[0], XA0, "8192");  RD(A47[1], XA1, "8192");  \
  RD(A47[2], XA0, "10240"); RD(A47[3], XA1, "10240"); \
  RD(A47[4], XA0, "12288"); RD(A47[5], XA1, "12288"); \
  RD(A47[6], XA0, "14336"); RD(A47[7], XA1, "14336"); } while (0)

#define GEMM_MAIN_LOOP() do { \
  stTile(0, 0); stTile(1, 1); \
  VMCNT8(); \
  SBAR(); SB0(); \
  { const u32 xA0 = aA0, xA1 = aA1, xB0 = bA0, xB1 = bA1; \
    ISSUE_G1(xA0, xA1, xB0, xB1); } \
  _Pragma("unroll") \
  for (int t = 0; t < 8; t++) { \
    const u32 bo  = (u32)((t & 1) * 65536); \
    const u32 obo = (u32)(((t + 1) & 1) * 65536); \
    const u32 xA0 = aA0 + bo,  xA1 = aA1 + bo,  xB0 = bA0 + bo,  xB1 = bA1 + bo; \
    const u32 yA0 = aA0 + obo, yA1 = aA1 + obo, yB0 = bA0 + obo, yB1 = bA1 + obo; \
    LGKM0_SB(); \
    ISSUE_G2(xA0, xA1, xB0, xB1); \
    SB0(); \
    MFMA_Q(0, 0, A03, Bq); \
    LGKM8_SB(); \
    MFMA_Q(0, 2, A03, Bq2); \
    LGKM0_SB(); \
    MFMA_Q(4, 0, A47, Bq); \
    VMCNT0(); \
    SBAR(); SB0(); \
    if (t < 7) { ISSUE_G1(yA0, yA1, yB0, yB1); } \
    if (t < 6) { stTile(t & 1, t + 2); } \
    SB0(); \
    MFMA_Q(4, 2, A47, Bq2); \
  } } while (0)

// ---------------- kernel 4: sim = nn_feats @ features^T / T, fused lse + positives ----
__global__ __launch_bounds__(512, 2) void k_sim_gemm(
    const u16* __restrict__ featb, const u16* __restrict__ queueb,
    const int* __restrict__ nnidx,
    float2* __restrict__ lsep, float* __restrict__ pos) {
  __shared__ u16 lds[65536];
  const int tid = threadIdx.x;
  const int w = tid >> 6, lane = tid & 63;
  const int wr = w >> 2, wc = w & 3;
  const int li = lane & 15, lg = lane >> 4;
  const int bid = (int)blockIdx.x;
  const int wg = (bid & 7) * 32 + (bid >> 3);     // XCD swizzle (256 = 8x32)
  const int mt = wg & 15, ct = wg >> 4;
  const int brow = mt * 256, bcol = ct * 256;

  const int srw = tid >> 3;
  const int ssl = (tid & 7) ^ ((tid >> 3) & 7);
  const int ldsw = w * 512;
  const u16* pA[4]; const u16* pB[4];
  #pragma unroll
  for (int h = 0; h < 2; h++)
    #pragma unroll
    for (int l = 0; l < 2; l++) {
      pA[h*2+l] = queueb + (size_t)nnidx[brow + h*128 + l*64 + srw] * DDIM + ssl * 8;
      pB[h*2+l] = featb  + (size_t)(bcol + h*128 + l*64 + srw) * DDIM + ssl * 8;
    }

  const int sx = li & 7;
  const int u0 = (lg ^ sx) * 8;
  const int u1 = ((4 + lg) ^ sx) * 8;
  const int aBase = wr * 8192 + li * 64;
  const int bBase = 16384 + (wc >> 1) * 8192 + ((wc & 1) * 64 + li) * 64;
  const u32 aA0 = (u32)(size_t)(las_ptr)&lds[aBase + u0];
  const u32 aA1 = (u32)(size_t)(las_ptr)&lds[aBase + u1];
  const u32 bA0 = (u32)(size_t)(las_ptr)&lds[bBase + u0];
  const u32 bA1 = (u32)(size_t)(las_ptr)&lds[bBase + u1];

  f32x4_t acc[8][4] = {};

  auto stTile = [&](int b, int t) {
    #pragma unroll
    for (int h = 0; h < 2; h++)
      #pragma unroll
      for (int l = 0; l < 2; l++)
        __builtin_amdgcn_global_load_lds((gas_ptr)(pA[h*2+l] + t * 64),
            (las_ptr)&lds[b * 32768 + h * 8192 + l * 4096 + ldsw], 16, 0, 0);
    #pragma unroll
    for (int h = 0; h < 2; h++)
      #pragma unroll
      for (int l = 0; l < 2; l++)
        __builtin_amdgcn_global_load_lds((gas_ptr)(pB[h*2+l] + t * 64),
            (las_ptr)&lds[b * 32768 + 16384 + h * 8192 + l * 4096 + ldsw], 16, 0, 0);
  };

  bf16x8_t A03[8], A47[8], Bq[4], Bq2[4];

  GEMM_MAIN_LOOP();

  // epilogue: scale by 1/T=2, positives, diag mask, per-row (max, sumexp) over 64 cols
  #pragma unroll
  for (int m = 0; m < 8; m++) {
    #pragma unroll
    for (int j = 0; j < 4; j++) {
      int row = brow + wr * 128 + m * 16 + lg * 4 + j;
      float vals[4];
      float vmax = -3.0e38f;
      #pragma unroll
      for (int n = 0; n < 4; n++) {
        int col = bcol + wc * 64 + n * 16 + li;
        float v = acc[m][n][j] * 2.0f;
        if (col == (row ^ NHALF)) pos[row] = v;   // positive sample (unique writer)
        if (col == row) v = -1.0e30f;             // diag mask
        vals[n] = v;
        vmax = fmaxf(vmax, v);
      }
      float sum = 0.f;
      #pragma unroll
      for (int n = 0; n < 4; n++) sum += __expf(vals[n] - vmax);
      #pragma unroll
      for (int off = 1; off < 16; off <<= 1) {
        float mo = __shfl_xor(vmax, off);
        float so = __shfl_xor(sum, off);
        float M = fmaxf(vmax, mo);
        sum = sum * __expf(vmax - M) + so * __expf(mo - M);
        vmax = M;
      }
      if (li == 0) lsep[(size_t)row * 64 + (ct * 4 + wc)] = make_float2(vmax, sum);
    }
  }
}

// ---------------- kernel 5: per-row logsumexp merge ----------------
__global__ void k_lse(const float2* __restrict__ lsep, float* __restrict__ lse) {
  int row = (int)((blockIdx.x * blockDim.x + threadIdx.x) >> 6);
  int lane = threadIdx.x & 63;
  float2 p = lsep[(size_t)row * 64 + lane];
  float m = p.x, s = p.y;
  #pragma unroll
  for (int off = 1; off < 64; off <<= 1) {
    float mo = __shfl_xor(m, off), so = __shfl_xor(s, off);
    float M = fmaxf(m, mo);
    s = s * __expf(m - M) + so * __expf(mo - M);
    m = M;
  }
  if (lane == 0) lse[row] = m + __logf(s);
}

// ---------------- kernel 6: final scalar ----------------
__global__ void k_final(const float* __restrict__ lse, const float* __restrict__ pos,
                        float* __restrict__ out) {
  __shared__ float red[4];
  int tid = threadIdx.x;
  float a = 0.f;
  for (int i = tid; i < NFEAT; i += 256) a += lse[i] - pos[i];
  #pragma unroll
  for (int off = 32; off >= 1; off >>= 1) a += __shfl_xor(a, off);
  if ((tid & 63) == 0) red[tid >> 6] = a;
  __syncthreads();
  if (tid == 0) out[0] = (red[0] + red[1] + red[2] + red[3]) / (float)NFEAT;
}

extern "C" void kernel_launch(void* const* d_in, const int* in_sizes, int n_in,
                              void* d_out, int out_size, void* d_ws, size_t ws_size,
                              hipStream_t stream) {
  const float* zi    = (const float*)d_in[0];
  const float* zj    = (const float*)d_in[1];
  const float* queue = (const float*)d_in[2];
  float* out = (float*)d_out;
  char* ws = (char*)d_ws;

  // ws layout (bytes):
  u16*    queueb  = (u16*)(ws + 0);              // 32768*512*2 = 33554432
  u16*    featb   = (u16*)(ws + 33554432);       // 4096*512*2  = 4194304
  u8*     queue8T = (u8*)(ws + 37748736);        // 32768*512   = 16777216
  u8*     feat8T  = (u8*)(ws + 54525952);        // 4096*512    = 2097152
  u64*    part    = (u64*)(ws + 56623104);       // 4096*512*8  = 16777216
  int*    nnidx   = (int*)(ws + 73400320);       // 4096*4      = 16384
  float2* lsep    = (float2*)(ws + 73416704);    // 4096*64*8   = 2097152
  float*  pos     = (float*)(ws + 75513856);     // 4096*4      = 16384
  float*  lse     = (float*)(ws + 75530240);     // 4096*4      = 16384
  // total = 75546624 bytes (~72 MB)

  k_norm<<<9216, 256, 0, stream>>>(zi, zj, queue, featb, queueb, feat8T, queue8T);
  k_argmax_gemm8<<<8192, 256, 0, stream>>>(feat8T, queue8T, part);
  k_argmax_reduce<<<1024, 256, 0, stream>>>(part, nnidx);
  k_sim_gemm<<<256, 512, 0, stream>>>(featb, queueb, nnidx, lsep, pos);
  k_lse<<<1024, 256, 0, stream>>>(lsep, lse);
  k_final<<<1, 256, 0, stream>>>(lse, pos, out);
}

// Round 12
// 131.821 us; speedup vs baseline: 3.9595x; 2.2031x over previous
//
#include <hip/hip_runtime.h>
#include <cstdint>

#define NFEAT 4096
#define NHALF 2048
#define DDIM  512
#define QROWS 32768

typedef unsigned short u16;
typedef unsigned char  u8;
typedef unsigned int   u32;
typedef unsigned long long u64;

typedef __bf16 bf16x8_t __attribute__((ext_vector_type(8)));
typedef float  f32x4_t  __attribute__((ext_vector_type(4)));
typedef float  f32x16_t __attribute__((ext_vector_type(16)));
typedef int    i32x4_t  __attribute__((ext_vector_type(4)));
typedef int    i32x8_t  __attribute__((ext_vector_type(8)));

typedef const __attribute__((address_space(1))) void* gas_ptr;
typedef __attribute__((address_space(3))) void* las_ptr;

__device__ __forceinline__ u16 f2bf(float f) {
  u32 u = __float_as_uint(f);
  u32 r = u + 0x7FFFu + ((u >> 16) & 1u);
  return (u16)(r >> 16);
}

// monotonic unsigned encoding of float (no NaN/Inf expected)
__device__ __forceinline__ u32 fkey(float f) {
  u32 u = __float_as_uint(f);
  return (u & 0x80000000u) ? ~u : (u | 0x80000000u);
}

// ---------------- kernel 1: l2-normalize rows -> bf16 + TILED fp8(e4m3) -------
// fp8 buffers stored PRE-TILED in the GEMM's fragment order: addr(row,k) =
// (row>>5)*16384 + (k>>6)*2048 + ((k>>5)&1)*1024 + ((k>>4)&1)*512 +
// (row&31)*16 + (k&15).  (verified R11, absmax 0.0)
__global__ void k_norm(const float* __restrict__ zi, const float* __restrict__ zj,
                       const float* __restrict__ queue,
                       u16* __restrict__ featb, u16* __restrict__ queueb,
                       u8* __restrict__ feat8T, u8* __restrict__ queue8T) {
  int gw = (int)((blockIdx.x * blockDim.x + threadIdx.x) >> 6);
  int lane = threadIdx.x & 63;
  const float* src; u16* dst; u8* dstT; int r31;
  if (gw < NFEAT) {
    src = (gw < NHALF) ? (zi + (size_t)gw * DDIM) : (zj + (size_t)(gw - NHALF) * DDIM);
    dst = featb + (size_t)gw * DDIM;
    dstT = feat8T + (size_t)(gw >> 5) * 16384; r31 = gw & 31;
  } else {
    int r = gw - NFEAT;
    src = queue + (size_t)r * DDIM;
    dst = queueb + (size_t)r * DDIM;
    dstT = queue8T + (size_t)(r >> 5) * 16384; r31 = r & 31;
  }
  float4 v0 = reinterpret_cast<const float4*>(src)[lane * 2];
  float4 v1 = reinterpret_cast<const float4*>(src)[lane * 2 + 1];
  float ss = v0.x*v0.x + v0.y*v0.y + v0.z*v0.z + v0.w*v0.w
           + v1.x*v1.x + v1.y*v1.y + v1.z*v1.z + v1.w*v1.w;
  #pragma unroll
  for (int off = 32; off >= 1; off >>= 1) ss += __shfl_xor(ss, off);
  float inv = 1.0f / fmaxf(sqrtf(ss), 1e-12f);
  float n0 = v0.x*inv, n1 = v0.y*inv, n2 = v0.z*inv, n3 = v0.w*inv;
  float n4 = v1.x*inv, n5 = v1.y*inv, n6 = v1.z*inv, n7 = v1.w*inv;
  ushort4 o0, o1;
  o0.x = f2bf(n0); o0.y = f2bf(n1); o0.z = f2bf(n2); o0.w = f2bf(n3);
  o1.x = f2bf(n4); o1.y = f2bf(n5); o1.z = f2bf(n6); o1.w = f2bf(n7);
  reinterpret_cast<ushort4*>(dst)[lane * 2]     = o0;
  reinterpret_cast<ushort4*>(dst)[lane * 2 + 1] = o1;
  u32 p01, p23, p45, p67;
  asm("v_cvt_pk_fp8_f32 %0, %1, %2" : "=v"(p01) : "v"(n0), "v"(n1));
  asm("v_cvt_pk_fp8_f32 %0, %1, %2" : "=v"(p23) : "v"(n2), "v"(n3));
  asm("v_cvt_pk_fp8_f32 %0, %1, %2" : "=v"(p45) : "v"(n4), "v"(n5));
  asm("v_cvt_pk_fp8_f32 %0, %1, %2" : "=v"(p67) : "v"(n6), "v"(n7));
  uint2 w8;
  w8.x = (p01 & 0xFFFFu) | (p23 << 16);
  w8.y = (p45 & 0xFFFFu) | (p67 << 16);
  size_t toff = (size_t)(lane >> 3) * 2048 + ((lane >> 2) & 1) * 1024
              + ((lane >> 1) & 1) * 512 + r31 * 16 + (lane & 1) * 8;
  *reinterpret_cast<uint2*>(dstT + toff) = w8;
}

#define SB0() __builtin_amdgcn_sched_barrier(0)
#define LGKM0_SB() do { asm volatile("s_waitcnt lgkmcnt(0)" ::: "memory"); SB0(); } while (0)
#define LGKM8_SB() do { asm volatile("s_waitcnt lgkmcnt(8)" ::: "memory"); SB0(); } while (0)
#define VMCNT8() asm volatile("s_waitcnt vmcnt(8)" ::: "memory")
#define VMCNT4() asm volatile("s_waitcnt vmcnt(4)" ::: "memory")
#define VMCNT0() asm volatile("s_waitcnt vmcnt(0)" ::: "memory")
#define SBAR() __builtin_amdgcn_s_barrier()
#define RD(dst, base, off) asm volatile("ds_read_b128 %0, %1 offset:" off \
                                        : "=v"(dst) : "v"(base))

// ---------------- kernel 2: fp8 MX GEMM queue @ feat^T + fused col-argmax -----
// R12 = R11's verified tile engine, TRANSPOSED: A = queue tile (M = 32768),
// B = feat tile (N = 4096). The per-feature argmax over queue rows now runs
// down a COLUMN = fixed lane -> in-register strict-greater scan (3 VALU/val,
// exact smallest-index tie-break via ascending-row iteration), one u64
// shfl_xor(32) to merge hi halves (packed fkey<<32|~q), one store. This
// removes the 320-DS/wave butterfly (LDS pipe was ~99us of R11's 246us).
// Grid 256 mt x 32 ft; part[f][mt*2+wr] -> same 4096x512 buffer + reducer.
// Block 4 waves/256thr, tile 128x128, wave 64(M)x64(N); FRAGMENT-ORDERED LDS
// slot L = mb*128 + hi_k*64 + s*32 + r31 (conflict-free, verified). Ring-3
// ledger verified R10: stage t+2 during t; boundary vmcnt(4); t=6 vmcnt(0).
#define MFMA8(ACC, AV, BV) \
  ACC = __builtin_amdgcn_mfma_scale_f32_32x32x64_f8f6f4(AV, BV, ACC, 0, 0, 0, \
        0x7F7F7F7F, 0, 0x7F7F7F7F)

#define FP8_TILE(XA, XB) do { \
    i32x4_t a00, a01, a10, a11, b00, b01, b10, b11; \
    RD(a00, XA, "0"); RD(a01, XA, "512"); \
    RD(a10, XA, "2048"); RD(a11, XA, "2560"); \
    RD(b00, XB, "0"); RD(b01, XB, "512"); \
    RD(b10, XB, "2048"); RD(b11, XB, "2560"); \
    LGKM0_SB(); \
    i32x8_t A0 = __builtin_shufflevector(a00, a01, 0, 1, 2, 3, 4, 5, 6, 7); \
    i32x8_t A1 = __builtin_shufflevector(a10, a11, 0, 1, 2, 3, 4, 5, 6, 7); \
    i32x8_t B0 = __builtin_shufflevector(b00, b01, 0, 1, 2, 3, 4, 5, 6, 7); \
    i32x8_t B1 = __builtin_shufflevector(b10, b11, 0, 1, 2, 3, 4, 5, 6, 7); \
    __builtin_amdgcn_s_setprio(1); \
    MFMA8(acc00, A0, B0); \
    MFMA8(acc01, A0, B1); \
    MFMA8(acc10, A1, B0); \
    MFMA8(acc11, A1, B1); \
    __builtin_amdgcn_s_setprio(0); \
  } while (0)

__global__ __launch_bounds__(256, 2) void k_argmax_gemm8(
    const u8* __restrict__ feat8T, const u8* __restrict__ queue8T,
    u64* __restrict__ part) {
  __shared__ u8 lds[49152];
  const int tid = threadIdx.x;
  const int w = tid >> 6, lane = tid & 63;
  const int wr = w >> 1, wc = w & 1;         // wr: queue(M)-dim wave, wc: feat(N)-dim
  const int l31 = lane & 31, hi = lane >> 5;
  const int bid = (int)blockIdx.x;
  const int wg = (bid & 7) * 1024 + (bid >> 3);  // bijective XCD swizzle (8192 = 8x1024)
  const int mt = wg >> 5, ft = wg & 31;      // ft fastest: queue slice L2-resident per XCD
  const int brow = mt * 128, bcol = ft * 128;

  // contiguous staging (pre-tiled source): A = queue rows, B = feat rows
  const u8* pA = queue8T + (size_t)(brow >> 5) * 16384 + (tid >> 7) * 16384 + (tid & 127) * 16;
  const u8* pB = feat8T  + (size_t)(bcol >> 5) * 16384 + (tid >> 7) * 16384 + (tid & 127) * 16;
  const u32 dA = (u32)(size_t)(las_ptr)&lds[tid * 16];
  const u32 dB = dA + 8192;

  // read-side standing addresses; m/n/s/buf via literal offsets
  const u32 aAd = (u32)(size_t)(las_ptr)&lds[wr * 4096 + hi * 1024 + l31 * 16];
  const u32 bAd = (u32)(size_t)(las_ptr)&lds[8192 + wc * 4096 + hi * 1024 + l31 * 16];

  f32x16_t acc00 = {}, acc01 = {}, acc10 = {}, acc11 = {};

  auto stage = [&](int b, int t) {
    const u32 base = (u32)(b * 16384);
    __builtin_amdgcn_global_load_lds((gas_ptr)(pA + t * 2048),         (las_ptr)(size_t)(dA + base), 16, 0, 0);
    __builtin_amdgcn_global_load_lds((gas_ptr)(pA + 32768 + t * 2048), (las_ptr)(size_t)(dA + base + 4096), 16, 0, 0);
    __builtin_amdgcn_global_load_lds((gas_ptr)(pB + t * 2048),         (las_ptr)(size_t)(dB + base), 16, 0, 0);
    __builtin_amdgcn_global_load_lds((gas_ptr)(pB + 32768 + t * 2048), (las_ptr)(size_t)(dB + base + 4096), 16, 0, 0);
  };

  stage(0, 0); stage(1, 1);
  VMCNT4();
  SBAR();

  #pragma unroll
  for (int t = 0; t < 8; t++) {
    if (t <= 5) stage((t + 2) % 3, t + 2);
    const u32 bb = (u32)((t % 3) * 16384);
    FP8_TILE(aAd + bb, bAd + bb);
    if (t < 7) {
      if (t <= 5) VMCNT4(); else VMCNT0();
      SBAR();
    }
  }

  // epilogue: per-feature (column = lane) argmax over this wave's 64 queue rows.
  // C/D 32x32: col = lane&31 (feat), row = (reg&3) + 8*(reg>>2) + 4*hi (+m*32).
  // In-register ascending-row scan w/ strict > keeps smallest row on ties;
  // hi halves merged via packed key (fkey<<32 | ~q) -> exact argmax semantics.
  const int mslot = mt * 2 + wr;
  const int fbase = bcol + wc * 64 + l31;
  #pragma unroll
  for (int n = 0; n < 2; n++) {
    float bv = -3.0e38f; int br = 0;
    #pragma unroll
    for (int m = 0; m < 2; m++) {
      #pragma unroll
      for (int reg = 0; reg < 16; reg++) {
        float v = n == 0 ? (m == 0 ? acc00[reg] : acc10[reg])
                         : (m == 0 ? acc01[reg] : acc11[reg]);
        int lr = m * 32 + (reg & 3) + 8 * (reg >> 2);   // ascending over (m,reg)
        if (v > bv) { bv = v; br = lr; }
      }
    }
    u32 q = (u32)(brow + wr * 64 + br + 4 * hi);
    u64 key = ((u64)fkey(bv) << 32) | (u64)(0xFFFFFFFFu - q);
    u64 o = __shfl_xor(key, 32);
    key = key > o ? key : o;
    if (hi == 0) part[(size_t)(fbase + n * 32) * 512 + mslot] = key;
  }
}

// ---------------- kernel 3: reduce argmax partials -> nn_idx ----------------
__global__ void k_argmax_reduce(const u64* __restrict__ part, int* __restrict__ nnidx) {
  int row = (int)((blockIdx.x * blockDim.x + threadIdx.x) >> 6);
  int lane = threadIdx.x & 63;
  const u64* p = part + (size_t)row * 512;
  u64 best = 0;
  #pragma unroll
  for (int i = 0; i < 8; i++) { u64 v = p[lane * 8 + i]; best = best > v ? best : v; }
  #pragma unroll
  for (int off = 1; off < 64; off <<= 1) { u64 o = __shfl_xor(best, off); best = best > o ? best : o; }
  if (lane == 0) nnidx[row] = (int)(0xFFFFFFFFu - (u32)(best & 0xFFFFFFFFu));
}

// ---------------- bf16 pipelined GEMM pieces (k_sim_gemm, R7 structure) ----------
#define MFMA_Q(MB, NB, AF, BF) do { \
  __builtin_amdgcn_s_setprio(1); \
  _Pragma("unroll") \
  for (int kk_ = 0; kk_ < 2; kk_++) \
    _Pragma("unroll") \
    for (int m_ = 0; m_ < 4; m_++) \
      _Pragma("unroll") \
      for (int n_ = 0; n_ < 2; n_++) \
        acc[MB + m_][NB + n_] = __builtin_amdgcn_mfma_f32_16x16x32_bf16( \
            AF[m_*2+kk_], BF[n_*2+kk_], acc[MB+m_][NB+n_], 0, 0, 0); \
  __builtin_amdgcn_s_setprio(0); } while (0)

#define ISSUE_G1(XA0, XA1, XB0, XB1) do { \
  RD(Bq[0],  XB0, "0");    RD(Bq[1],  XB1, "0");    \
  RD(Bq[2],  XB0, "2048"); RD(Bq[3],  XB1, "2048"); \
  RD(A03[0], XA0, "0");    RD(A03[1], XA1, "0");    \
  RD(A03[2], XA0, "2048"); RD(A03[3], XA1, "2048"); \
  RD(A03[4], XA0, "4096"); RD(A03[5], XA1, "4096"); \
  RD(A03[6], XA0, "6144"); RD(A03[7], XA1, "6144"); } while (0)

#define ISSUE_G2(XA0, XA1, XB0, XB1) do { \
  RD(Bq2[0], XB0, "4096");  RD(Bq2[1], XB1, "4096");  \
  RD(Bq2[2], XB0, "6144");  RD(Bq2[3], XB1, "6144");  \
  RD(A47[0], XA0, "8192");  RD(A47[1], XA1, "8192");  \
  RD(A47[2], XA0, "10240"); RD(A47[3], XA1, "10240"); \
  RD(A47[4], XA0, "12288"); RD(A47[5], XA1, "12288"); \
  RD(A47[6], XA0, "14336"); RD(A47[7], XA1, "14336"); } while (0)

#define GEMM_MAIN_LOOP() do { \
  stTile(0, 0); stTile(1, 1); \
  VMCNT8(); \
  SBAR(); SB0(); \
  { const u32 xA0 = aA0, xA1 = aA1, xB0 = bA0, xB1 = bA1; \
    ISSUE_G1(xA0, xA1, xB0, xB1); } \
  _Pragma("unroll") \
  for (int t = 0; t < 8; t++) { \
    const u32 bo  = (u32)((t & 1) * 65536); \
    const u32 obo = (u32)(((t + 1) & 1) * 65536); \
    const u32 xA0 = aA0 + bo,  xA1 = aA1 + bo,  xB0 = bA0 + bo,  xB1 = bA1 + bo; \
    const u32 yA0 = aA0 + obo, yA1 = aA1 + obo, yB0 = bA0 + obo, yB1 = bA1 + obo; \
    LGKM0_SB(); \
    ISSUE_G2(xA0, xA1, xB0, xB1); \
    SB0(); \
    MFMA_Q(0, 0, A03, Bq); \
    LGKM8_SB(); \
    MFMA_Q(0, 2, A03, Bq2); \
    LGKM0_SB(); \
    MFMA_Q(4, 0, A47, Bq); \
    VMCNT0(); \
    SBAR(); SB0(); \
    if (t < 7) { ISSUE_G1(yA0, yA1, yB0, yB1); } \
    if (t < 6) { stTile(t & 1, t + 2); } \
    SB0(); \
    MFMA_Q(4, 2, A47, Bq2); \
  } } while (0)

// ---------------- kernel 4: sim = nn_feats @ features^T / T, fused lse + positives ----
__global__ __launch_bounds__(512, 2) void k_sim_gemm(
    const u16* __restrict__ featb, const u16* __restrict__ queueb,
    const int* __restrict__ nnidx,
    float2* __restrict__ lsep, float* __restrict__ pos) {
  __shared__ u16 lds[65536];
  const int tid = threadIdx.x;
  const int w = tid >> 6, lane = tid & 63;
  const int wr = w >> 2, wc = w & 3;
  const int li = lane & 15, lg = lane >> 4;
  const int bid = (int)blockIdx.x;
  const int wg = (bid & 7) * 32 + (bid >> 3);     // XCD swizzle (256 = 8x32)
  const int mt = wg & 15, ct = wg >> 4;
  const int brow = mt * 256, bcol = ct * 256;

  const int srw = tid >> 3;
  const int ssl = (tid & 7) ^ ((tid >> 3) & 7);
  const int ldsw = w * 512;
  const u16* pA[4]; const u16* pB[4];
  #pragma unroll
  for (int h = 0; h < 2; h++)
    #pragma unroll
    for (int l = 0; l < 2; l++) {
      pA[h*2+l] = queueb + (size_t)nnidx[brow + h*128 + l*64 + srw] * DDIM + ssl * 8;
      pB[h*2+l] = featb  + (size_t)(bcol + h*128 + l*64 + srw) * DDIM + ssl * 8;
    }

  const int sx = li & 7;
  const int u0 = (lg ^ sx) * 8;
  const int u1 = ((4 + lg) ^ sx) * 8;
  const int aBase = wr * 8192 + li * 64;
  const int bBase = 16384 + (wc >> 1) * 8192 + ((wc & 1) * 64 + li) * 64;
  const u32 aA0 = (u32)(size_t)(las_ptr)&lds[aBase + u0];
  const u32 aA1 = (u32)(size_t)(las_ptr)&lds[aBase + u1];
  const u32 bA0 = (u32)(size_t)(las_ptr)&lds[bBase + u0];
  const u32 bA1 = (u32)(size_t)(las_ptr)&lds[bBase + u1];

  f32x4_t acc[8][4] = {};

  auto stTile = [&](int b, int t) {
    #pragma unroll
    for (int h = 0; h < 2; h++)
      #pragma unroll
      for (int l = 0; l < 2; l++)
        __builtin_amdgcn_global_load_lds((gas_ptr)(pA[h*2+l] + t * 64),
            (las_ptr)&lds[b * 32768 + h * 8192 + l * 4096 + ldsw], 16, 0, 0);
    #pragma unroll
    for (int h = 0; h < 2; h++)
      #pragma unroll
      for (int l = 0; l < 2; l++)
        __builtin_amdgcn_global_load_lds((gas_ptr)(pB[h*2+l] + t * 64),
            (las_ptr)&lds[b * 32768 + 16384 + h * 8192 + l * 4096 + ldsw], 16, 0, 0);
  };

  bf16x8_t A03[8], A47[8], Bq[4], Bq2[4];

  GEMM_MAIN_LOOP();

  // epilogue: scale by 1/T=2, positives, diag mask, per-row (max, sumexp) over 64 cols
  #pragma unroll
  for (int m = 0; m < 8; m++) {
    #pragma unroll
    for (int j = 0; j < 4; j++) {
      int row = brow + wr * 128 + m * 16 + lg * 4 + j;
      float vals[4];
      float vmax = -3.0e38f;
      #pragma unroll
      for (int n = 0; n < 4; n++) {
        int col = bcol + wc * 64 + n * 16 + li;
        float v = acc[m][n][j] * 2.0f;
        if (col == (row ^ NHALF)) pos[row] = v;   // positive sample (unique writer)
        if (col == row) v = -1.0e30f;             // diag mask
        vals[n] = v;
        vmax = fmaxf(vmax, v);
      }
      float sum = 0.f;
      #pragma unroll
      for (int n = 0; n < 4; n++) sum += __expf(vals[n] - vmax);
      #pragma unroll
      for (int off = 1; off < 16; off <<= 1) {
        float mo = __shfl_xor(vmax, off);
        float so = __shfl_xor(sum, off);
        float M = fmaxf(vmax, mo);
        sum = sum * __expf(vmax - M) + so * __expf(mo - M);
        vmax = M;
      }
      if (li == 0) lsep[(size_t)row * 64 + (ct * 4 + wc)] = make_float2(vmax, sum);
    }
  }
}

// ---------------- kernel 5: per-row logsumexp merge ----------------
__global__ void k_lse(const float2* __restrict__ lsep, float* __restrict__ lse) {
  int row = (int)((blockIdx.x * blockDim.x + threadIdx.x) >> 6);
  int lane = threadIdx.x & 63;
  float2 p = lsep[(size_t)row * 64 + lane];
  float m = p.x, s = p.y;
  #pragma unroll
  for (int off = 1; off < 64; off <<= 1) {
    float mo = __shfl_xor(m, off), so = __shfl_xor(s, off);
    float M = fmaxf(m, mo);
    s = s * __expf(m - M) + so * __expf(mo - M);
    m = M;
  }
  if (lane == 0) lse[row] = m + __logf(s);
}

// ---------------- kernel 6: final scalar ----------------
__global__ void k_final(const float* __restrict__ lse, const float* __restrict__ pos,
                        float* __restrict__ out) {
  __shared__ float red[4];
  int tid = threadIdx.x;
  float a = 0.f;
  for (int i = tid; i < NFEAT; i += 256) a += lse[i] - pos[i];
  #pragma unroll
  for (int off = 32; off >= 1; off >>= 1) a += __shfl_xor(a, off);
  if ((tid & 63) == 0) red[tid >> 6] = a;
  __syncthreads();
  if (tid == 0) out[0] = (red[0] + red[1] + red[2] + red[3]) / (float)NFEAT;
}

extern "C" void kernel_launch(void* const* d_in, const int* in_sizes, int n_in,
                              void* d_out, int out_size, void* d_ws, size_t ws_size,
                              hipStream_t stream) {
  const float* zi    = (const float*)d_in[0];
  const float* zj    = (const float*)d_in[1];
  const float* queue = (const float*)d_in[2];
  float* out = (float*)d_out;
  char* ws = (char*)d_ws;

  // ws layout (bytes):
  u16*    queueb  = (u16*)(ws + 0);              // 32768*512*2 = 33554432
  u16*    featb   = (u16*)(ws + 33554432);       // 4096*512*2  = 4194304
  u8*     queue8T = (u8*)(ws + 37748736);        // 32768*512   = 16777216
  u8*     feat8T  = (u8*)(ws + 54525952);        // 4096*512    = 2097152
  u64*    part    = (u64*)(ws + 56623104);       // 4096*512*8  = 16777216
  int*    nnidx   = (int*)(ws + 73400320);       // 4096*4      = 16384
  float2* lsep    = (float2*)(ws + 73416704);    // 4096*64*8   = 2097152
  float*  pos     = (float*)(ws + 75513856);     // 4096*4      = 16384
  float*  lse     = (float*)(ws + 75530240);     // 4096*4      = 16384
  // total = 75546624 bytes (~72 MB)

  k_norm<<<9216, 256, 0, stream>>>(zi, zj, queue, featb, queueb, feat8T, queue8T);
  k_argmax_gemm8<<<8192, 256, 0, stream>>>(feat8T, queue8T, part);
  k_argmax_reduce<<<1024, 256, 0, stream>>>(part, nnidx);
  k_sim_gemm<<<256, 512, 0, stream>>>(featb, queueb, nnidx, lsep, pos);
  k_lse<<<1024, 256, 0, stream>>>(lsep, lse);
  k_final<<<1, 256, 0, stream>>>(lse, pos, out);
}